// Round 7
// baseline (420.156 us; speedup 1.0000x reference)
//
#include <hip/hip_runtime.h>
#include <math.h>

#define PIX 36864          // 192*192
#define IMW 192
#define NWIN 4465          // 47*95
#define NWIN_W 95
#define NTASK (NWIN * 6)

typedef short bf16x8 __attribute__((ext_vector_type(8)));
typedef short bf16x4 __attribute__((ext_vector_type(4)));
typedef float floatx4 __attribute__((ext_vector_type(4)));

#if defined(__has_builtin)
#  if __has_builtin(__builtin_amdgcn_rcpf)
#    define RCP(x) __builtin_amdgcn_rcpf(x)
#  endif
#endif
#ifndef RCP
#  define RCP(x) (1.0f / (x))
#endif

__device__ __forceinline__ unsigned short f2bf(float f) {
    union { float f; unsigned u; } v; v.f = f;
    unsigned r = v.u + 0x7fff + ((v.u >> 16) & 1);   // RNE
    return (unsigned short)(r >> 16);
}
__device__ __forceinline__ float bf2f(unsigned short b) {
    union { unsigned u; float f; } v; v.u = ((unsigned)b) << 16;
    return v.f;
}

// ======================= build stacked complex weight matrices =======================
// A is (2M x 2K) bf16, rows/cols in 16-granule interleave:
//   row 32*(r>>4)+(r&15)   = real-out row of channel r  -> [Wr | -Wi]
//   row 32*(r>>4)+16+(r&15) = imag-out row              -> [Wi |  Wr]
// col 32*(k>>4)+(k&15) = real k, +16 = imag k.
__device__ __forceinline__ void emit_w(
    const float* __restrict__ wr, const float* __restrict__ wi,
    unsigned short* __restrict__ A, int M, int K, int e)
{
    int r = e / K, k = e % K;
    int K2 = 2 * K;
    int rr = 32 * (r >> 4) + (r & 15);
    int cc = 32 * (k >> 4) + (k & 15);
    unsigned short br = f2bf(wr[e]);
    unsigned short bi = f2bf(wi[e]);
    A[(size_t)rr * K2 + cc]             = br;
    A[(size_t)rr * K2 + cc + 16]        = bi ^ 0x8000;
    A[(size_t)(rr + 16) * K2 + cc]      = bi;
    A[(size_t)(rr + 16) * K2 + cc + 16] = br;
}

__global__ __launch_bounds__(256) void wconv_all_kernel(
    const float* __restrict__ qwr, const float* __restrict__ qwi,
    const float* __restrict__ pwr, const float* __restrict__ pwi,
    const float* __restrict__ w1r, const float* __restrict__ w1i,
    const float* __restrict__ w2r, const float* __restrict__ w2i,
    unsigned short* __restrict__ Aq, unsigned short* __restrict__ Ap,
    unsigned short* __restrict__ A1, unsigned short* __restrict__ A2,
    float* __restrict__ ssum)
{
    int blk = blockIdx.x;
    if (blk == 432) {                       // zero BN stat accumulators (768+768? -> 1536 floats? no: 768)
        for (int j = threadIdx.x; j < 1536; j += 256) ssum[j] = 0.f;
        return;
    }
    if (blk < 108)      { emit_w(qwr, qwi, Aq, 288, 96, blk * 256 + threadIdx.x); }
    else if (blk < 144) { emit_w(pwr, pwi, Ap,  96, 96, (blk - 108) * 256 + threadIdx.x); }
    else if (blk < 288) { emit_w(w1r, w1i, A1, 384, 96, (blk - 144) * 256 + threadIdx.x); }
    else                { emit_w(w2r, w2i, A2,  96, 384, (blk - 288) * 256 + threadIdx.x); }
}

// ======================= pack fp32 planar (re,im) -> stacked k8-packed bf16 =======================
// B row k' granule map: kb = k'>>3 in 0..23 ; kt=kb>>2, comp=(kb>>1)&1, ch0 = kt*16+(kb&1)*8
__global__ __launch_bounds__(256) void pack_cat_kernel(
    const float* __restrict__ sr, const float* __restrict__ si,
    unsigned short* __restrict__ d, int N)
{
    int n  = blockIdx.x * 256 + threadIdx.x;
    int kb = blockIdx.y;
    int ch0 = (kb >> 2) * 16 + (kb & 1) * 8;
    const float* s = ((kb >> 1) & 1) ? si : sr;
    bf16x8 v;
#pragma unroll
    for (int j = 0; j < 8; ++j)
        ((unsigned short*)&v)[j] = f2bf(s[(size_t)(ch0 + j) * N + n]);
    *(bf16x8*)&d[((size_t)kb * N + n) * 8] = v;
}

// pack + BN1 apply fused
__global__ __launch_bounds__(256) void pack_bn_cat_kernel(
    const float* __restrict__ sr, const float* __restrict__ si,
    const float* __restrict__ stats,
    const float* __restrict__ gr, const float* __restrict__ br,
    const float* __restrict__ gi, const float* __restrict__ bi,
    unsigned short* __restrict__ d, int N)
{
    int n  = blockIdx.x * 256 + threadIdx.x;
    int kb = blockIdx.y;
    int c  = (kb >> 1) & 1;
    int ch0 = (kb >> 2) * 16 + (kb & 1) * 8;
    const float* s = c ? si : sr;
    const float* gg = c ? gi : gr;
    const float* bb = c ? bi : br;
    bf16x8 v;
#pragma unroll
    for (int j = 0; j < 8; ++j) {
        int ch = ch0 + j;
        float mean = stats[(c * 96 + ch) * 2];
        float isd  = stats[(c * 96 + ch) * 2 + 1];
        ((unsigned short*)&v)[j] = f2bf(gg[ch] * (s[(size_t)ch * N + n] - mean) * isd + bb[ch]);
    }
    *(bf16x8*)&d[((size_t)kb * N + n) * 8] = v;
}

// ======================= stacked real GEMM via MFMA =======================
// Y = A (Mtot x K2) * B (K2 x N, k8-packed). Block = 4 waves; wave tile 32 x (J*16).
// STORE: 0 fp32 planar split re/im (granule: t=0 re, t=1 im of ch=(m0>>1)+g*4+reg)
//        1 k8-packed bf16 (row = k' of next GEMM, identity) ; ACT=1: cgelu first
//        2 qkvb pixel-major slot
template<int K2, int J, int STORE, int ACT>
__global__ __launch_bounds__(256) void rgemm_kernel(
    const unsigned short* __restrict__ A,
    const unsigned short* __restrict__ B,
    float* __restrict__ Yr, float* __restrict__ Yi,
    unsigned short* __restrict__ P, int N)
{
    const int lane = threadIdx.x & 63;
    const int wave = threadIdx.x >> 6;
    const int g = lane >> 4;
    const int r = lane & 15;
    const int m0 = blockIdx.x * 32;
    const int n0 = (blockIdx.y * 4 + wave) * (J * 16);

    floatx4 acc[2][J];
#pragma unroll
    for (int t = 0; t < 2; ++t)
#pragma unroll
        for (int j = 0; j < J; ++j)
            acc[t][j] = (floatx4){0.f, 0.f, 0.f, 0.f};

    for (int kc = 0; kc < K2; kc += 32) {
        bf16x8 a0 = *(const bf16x8*)&A[(size_t)(m0 + r) * K2 + kc + g * 8];
        bf16x8 a1 = *(const bf16x8*)&A[(size_t)(m0 + 16 + r) * K2 + kc + g * 8];
        bf16x8 b[J];
#pragma unroll
        for (int jj = 0; jj < J; ++jj)
            b[jj] = *(const bf16x8*)&B[((size_t)((kc >> 3) + g) * N + n0 + jj * 16 + r) * 8];
#pragma unroll
        for (int jj = 0; jj < J; ++jj) {
            acc[0][jj] = __builtin_amdgcn_mfma_f32_16x16x32_bf16(a0, b[jj], acc[0][jj], 0, 0, 0);
            acc[1][jj] = __builtin_amdgcn_mfma_f32_16x16x32_bf16(a1, b[jj], acc[1][jj], 0, 0, 0);
        }
    }

    if (ACT == 1) {   // cgelu: re in acc[0], im in acc[1], same lane/reg = same element
#pragma unroll
        for (int jj = 0; jj < J; ++jj)
#pragma unroll
            for (int reg = 0; reg < 4; ++reg) {
                float a = acc[0][jj][reg], bv = acc[1][jj][reg];
                float mag = sqrtf(a * a + bv * bv);
                float f = (0.5f + 0.5f * erff(mag * 0.70710678118654752f)) * mag * RCP(mag + 1e-8f);
                acc[0][jj][reg] = a * f;
                acc[1][jj][reg] = bv * f;
            }
    }

    if (STORE == 0) {
#pragma unroll
        for (int jj = 0; jj < J; ++jj) {
            int col = n0 + jj * 16 + r;
#pragma unroll
            for (int reg = 0; reg < 4; ++reg) {
                int ch = (m0 >> 1) + g * 4 + reg;
                Yr[(size_t)ch * N + col] = acc[0][jj][reg];
                Yi[(size_t)ch * N + col] = acc[1][jj][reg];
            }
        }
    } else if (STORE == 1) {
#pragma unroll
        for (int t = 0; t < 2; ++t)
#pragma unroll
            for (int jj = 0; jj < J; ++jj) {
                int col = n0 + jj * 16 + r;
                size_t rowblk = (size_t)((m0 + t * 16 + g * 4) >> 3);
                int sub = (g & 1) * 4;
                bf16x4 pk;
#pragma unroll
                for (int reg = 0; reg < 4; ++reg)
                    ((unsigned short*)&pk)[reg] = f2bf(acc[t][jj][reg]);
                *(bf16x4*)&P[(rowblk * N + col) * 8 + sub] = pk;
            }
    } else {
        int ch0 = m0 >> 1;
        int which = ch0 / 96;
        int hh = (ch0 % 96) / 16;
#pragma unroll
        for (int jj = 0; jj < J; ++jj) {
            int col = n0 + jj * 16 + r;      // pixel
            size_t sb = (((size_t)col * 3 + which) * 6 + hh) * 32;
#pragma unroll
            for (int t = 0; t < 2; ++t) {
                bf16x4 pk;
#pragma unroll
                for (int reg = 0; reg < 4; ++reg)
                    ((unsigned short*)&pk)[reg] = f2bf(acc[t][jj][reg]);
                *(bf16x4*)&P[sb + t * 16 + g * 4] = pk;
            }
        }
    }
}

// ======================= finalize BN stats =======================
__global__ __launch_bounds__(192) void finalize_stats_kernel(
    const float* __restrict__ ssum, float* __restrict__ stats)
{
    int idx = threadIdx.x;
    if (idx >= 192) return;
    float s  = ssum[idx * 2];
    float sq = ssum[idx * 2 + 1];
    float mean = s / (float)PIX;
    float var  = sq / (float)PIX - mean * mean;
    stats[idx * 2]     = mean;
    stats[idx * 2 + 1] = rsqrtf(var + 1e-5f);
}

// ======================= MFMA attention: one wave per (window, head) =======================
__global__ __launch_bounds__(256) void attn_mfma_kernel(
    const unsigned short* __restrict__ qkvb,
    const float* __restrict__ rel,
    unsigned short* __restrict__ wout)
{
    __shared__ unsigned aLDS[4][32 * 36];
    __shared__ unsigned vLDS[4][32 * 17];

    const int wv   = threadIdx.x >> 6;
    const int lane = threadIdx.x & 63;
    const int lr   = lane & 15;
    const int g    = lane >> 4;

    int t = blockIdx.x * 4 + wv;
    if (t >= NTASK) t = NTASK - 1;
    const int w = t / 6, h = t % 6;
    const int nh = w / NWIN_W, nw = w % NWIN_W;
    const int r0 = nh * 4, c0 = nw * 2;

    unsigned* AL = aLDS[wv];
    unsigned* VL = vLDS[wv];

    auto slot = [&](int p, int which) -> size_t {
        int gpix = (r0 + (p >> 2)) * IMW + c0 + (p & 3);
        return ((size_t)gpix * 18 + which * 6 + h) * 32;
    };

    // ---- stage V into LDS as (vr,vi) dword pairs [m][d] ----
    {
        int m = lane & 31;
        int half = lane >> 5;
        size_t sv = slot(m, 2);
        const bf16x8 vr = *(const bf16x8*)&qkvb[sv + half * 8];
        const bf16x8 vi = *(const bf16x8*)&qkvb[sv + 16 + half * 8];
#pragma unroll
        for (int j = 0; j < 8; ++j) {
            unsigned pk = (unsigned)(unsigned short)vr[j] |
                          ((unsigned)(unsigned short)vi[j] << 16);
            VL[m * 17 + half * 8 + j] = pk;
        }
    }

    // ---- Q/K fragments: half-select folded into address, conj via xor ----
    const int hoff = (g >> 1) * 16;
    const int loff = (g & 1) * 8;
    const unsigned sm = (g >= 2) ? 0x80008000u : 0u;
    bf16x8 Are[2], Aim[2], Bre[2], Bim[2];
#pragma unroll
    for (int tt = 0; tt < 2; ++tt) {
        size_t sq = slot(tt * 16 + lr, 0);
        size_t sk = slot(tt * 16 + lr, 1);
        Are[tt] = *(const bf16x8*)&qkvb[sq + hoff + loff];
        Aim[tt] = *(const bf16x8*)&qkvb[sq + (16 - hoff) + loff];
        Bre[tt] = *(const bf16x8*)&qkvb[sk + hoff + loff];
        bf16x8 tmp = Bre[tt];
        unsigned* u = (unsigned*)&tmp;
        u[0] ^= sm; u[1] ^= sm; u[2] ^= sm; u[3] ^= sm;
        Bim[tt] = tmp;
    }

    // ---- S = Q·conj(K)^T : 8 MFMAs ----
    const floatx4 z4 = (floatx4){0.f, 0.f, 0.f, 0.f};
    floatx4 Sre[2][2], Sim[2][2];
#pragma unroll
    for (int tn = 0; tn < 2; ++tn)
#pragma unroll
        for (int tm = 0; tm < 2; ++tm) {
            Sre[tn][tm] = __builtin_amdgcn_mfma_f32_16x16x32_bf16(Are[tn], Bre[tm], z4, 0, 0, 0);
            Sim[tn][tm] = __builtin_amdgcn_mfma_f32_16x16x32_bf16(Aim[tn], Bim[tm], z4, 0, 0, 0);
        }

    // ---- scale + bias, write RAW logits transposed into LDS ----
    const float* relh = rel + h * 105;
#pragma unroll
    for (int tn = 0; tn < 2; ++tn)
#pragma unroll
        for (int tm = 0; tm < 2; ++tm) {
            int m = tm * 16 + lr;
            int ym = m >> 2, xm = m & 3;
            int yn = tn * 4 + g;
            int bidx = (yn - ym + 7) * 7 + (3 - xm);
#pragma unroll
            for (int reg = 0; reg < 4; ++reg) {
                float re = Sre[tn][tm][reg] * 0.25f + relh[bidx + reg];
                float im = Sim[tn][tm][reg] * 0.25f;
                int n = tn * 16 + g * 4 + reg;
                AL[n * 36 + m] = (unsigned)f2bf(re) | ((unsigned)f2bf(im) << 16);
            }
        }
    __syncthreads();

    // ---- row-owner magnitude softmax: 2 lanes per row, 1 shuffle ----
    {
        const int row = lane & 31;
        const int half = lane >> 5;
        unsigned* rp = &AL[row * 36 + half * 16];
        unsigned pk[16];
        *(uint4*)&pk[0]  = *(const uint4*)&rp[0];
        *(uint4*)&pk[4]  = *(const uint4*)&rp[4];
        *(uint4*)&pk[8]  = *(const uint4*)&rp[8];
        *(uint4*)&pk[12] = *(const uint4*)&rp[12];
        float re[16], im[16], mg[16];
#pragma unroll
        for (int j = 0; j < 16; ++j) {
            union { unsigned u; float f; } a, b;
            a.u = pk[j] << 16;
            b.u = pk[j] & 0xffff0000u;
            re[j] = a.f; im[j] = b.f;
            mg[j] = sqrtf(a.f * a.f + b.f * b.f);
        }
        float mx = mg[0];
#pragma unroll
        for (int j = 1; j < 16; ++j) mx = fmaxf(mx, mg[j]);
        mx = fmaxf(mx, __shfl_xor(mx, 32, 64));
        float es[16], ss = 0.f;
#pragma unroll
        for (int j = 0; j < 16; ++j) { es[j] = __expf(mg[j] - mx); ss += es[j]; }
        ss += __shfl_xor(ss, 32, 64);
        float inv = RCP(ss);
#pragma unroll
        for (int j = 0; j < 16; ++j) {
            float f = es[j] * inv * RCP(mg[j] + 1e-8f);
            pk[j] = (unsigned)f2bf(re[j] * f) | ((unsigned)f2bf(im[j] * f) << 16);
        }
        *(uint4*)&rp[0]  = *(uint4*)&pk[0];
        *(uint4*)&rp[4]  = *(uint4*)&pk[4];
        *(uint4*)&rp[8]  = *(uint4*)&pk[8];
        *(uint4*)&rp[12] = *(uint4*)&pk[12];
    }
    __syncthreads();

    // ---- P = attn · V : 8 MFMAs ----
    floatx4 Pre[2] = {z4, z4}, Pim[2] = {z4, z4};
#pragma unroll
    for (int kc = 0; kc < 2; ++kc) {
        bf16x8 Bpr, Bpi;
        unsigned* bpr = (unsigned*)&Bpr;
        unsigned* bpi = (unsigned*)&Bpi;
#pragma unroll
        for (int p = 0; p < 4; ++p) {
            unsigned pv = VL[(kc * 16 + g * 4 + p) * 17 + lr];
            bpr[p] = pv ^ 0x80000000u;
            bpi[p] = (pv >> 16) | (pv << 16);
        }
#pragma unroll
        for (int tn = 0; tn < 2; ++tn) {
            bf16x8 Af = *(bf16x8*)&AL[(tn * 16 + lr) * 36 + kc * 16 + g * 4];
            Pre[tn] = __builtin_amdgcn_mfma_f32_16x16x32_bf16(Af, Bpr, Pre[tn], 0, 0, 0);
            Pim[tn] = __builtin_amdgcn_mfma_f32_16x16x32_bf16(Af, Bpi, Pim[tn], 0, 0, 0);
        }
    }

    // ---- epilogue ----
#pragma unroll
    for (int tn = 0; tn < 2; ++tn)
#pragma unroll
        for (int reg = 0; reg < 4; ++reg) {
            int n = tn * 16 + g * 4 + reg;
            int ch = h * 16 + lr;
            unsigned pk = (unsigned)f2bf(Pre[tn][reg]) |
                          ((unsigned)f2bf(Pim[tn][reg]) << 16);
            *(unsigned*)&wout[(((size_t)w * 32 + n) * 96 + ch) * 2] = pk;
        }
}

// ======================= fold + count-div + pack (stacked layout) for proj =======================
__global__ __launch_bounds__(256) void fold_pack_kernel(
    const unsigned short* __restrict__ wout,
    unsigned short* __restrict__ d)
{
    int e = blockIdx.x * 256 + threadIdx.x;   // PIX*12
    int gpix = e / 12;
    int cg   = e % 12;                        // channel group of 8
    int r = gpix / IMW, c = gpix % IMW;
    int nh0 = (r >= 7) ? ((r - 4) >> 2) : 0;
    int nh1 = min(46, r >> 2);
    int nw0 = (c >= 3) ? ((c - 2) >> 1) : 0;
    int nw1 = min(94, c >> 1);

    float accr[8] = {0,0,0,0,0,0,0,0}, acci[8] = {0,0,0,0,0,0,0,0};
    int cnt = 0;
    for (int nh = nh0; nh <= nh1; ++nh)
        for (int nw = nw0; nw <= nw1; ++nw) {
            int win = nh * NWIN_W + nw;
            int n = (r - nh * 4) * 4 + (c - nw * 2);
            const unsigned short* src = &wout[(((size_t)win * 32 + n) * 96 + cg * 8) * 2];
            bf16x8 a = *(const bf16x8*)&src[0];
            bf16x8 b = *(const bf16x8*)&src[8];
#pragma unroll
            for (int j = 0; j < 4; ++j) {
                accr[j]     += bf2f((unsigned short)a[j*2]);
                acci[j]     += bf2f((unsigned short)a[j*2+1]);
                accr[4 + j] += bf2f((unsigned short)b[j*2]);
                acci[4 + j] += bf2f((unsigned short)b[j*2+1]);
            }
            ++cnt;
        }
    float invc = 1.0f / ((float)cnt + 1e-8f);
    bf16x8 pr, pi;
#pragma unroll
    for (int j = 0; j < 8; ++j) {
        ((unsigned short*)&pr)[j] = f2bf(accr[j] * invc);
        ((unsigned short*)&pi)[j] = f2bf(acci[j] * invc);
    }
    // stacked k8 rows: kb_re = 4*(cg>>1)+(cg&1), kb_im = kb_re+2  (chans 8*cg..+7)
    int kb_re = 4 * (cg >> 1) + (cg & 1);
    *(bf16x8*)&d[((size_t)kb_re * PIX + gpix) * 8]       = pr;
    *(bf16x8*)&d[((size_t)(kb_re + 2) * PIX + gpix) * 8] = pi;
}

// ======================= fused elementwise + BN-stat kernels =======================
__device__ __forceinline__ void block_stats_commit(
    float s_r, float q_r, float s_i, float q_i, int ch, float* __restrict__ ssum)
{
#pragma unroll
    for (int msk = 1; msk < 64; msk <<= 1) {
        s_r += __shfl_xor(s_r, msk, 64);
        q_r += __shfl_xor(q_r, msk, 64);
        s_i += __shfl_xor(s_i, msk, 64);
        q_i += __shfl_xor(q_i, msk, 64);
    }
    __shared__ float red[4][4];
    const int wv = threadIdx.x >> 6;
    if ((threadIdx.x & 63) == 0) {
        red[wv][0] = s_r; red[wv][1] = q_r; red[wv][2] = s_i; red[wv][3] = q_i;
    }
    __syncthreads();
    if (threadIdx.x == 0) {
        float a0 = red[0][0] + red[1][0] + red[2][0] + red[3][0];
        float a1 = red[0][1] + red[1][1] + red[2][1] + red[3][1];
        float a2 = red[0][2] + red[1][2] + red[2][2] + red[3][2];
        float a3 = red[0][3] + red[1][3] + red[2][3] + red[3][3];
        atomicAdd(&ssum[ch * 2],            a0);
        atomicAdd(&ssum[ch * 2 + 1],        a1);
        atomicAdd(&ssum[(96 + ch) * 2],     a2);
        atomicAdd(&ssum[(96 + ch) * 2 + 1], a3);
    }
}

__global__ __launch_bounds__(256) void combine_stats_kernel(
    const float* __restrict__ xr, const float* __restrict__ xi,
    const float* __restrict__ pr, const float* __restrict__ pi,
    float* __restrict__ sr, float* __restrict__ si,
    float* __restrict__ ssum)
{
    const int ch = blockIdx.x / 36;
    const int pb = blockIdx.x % 36;
    const size_t idx = (size_t)ch * PIX + pb * 1024 + threadIdx.x * 4;
    float4 a = *(const float4*)&xr[idx];
    float4 b = *(const float4*)&pr[idx];
    float4 vr = {a.x + b.x, a.y + b.y, a.z + b.z, a.w + b.w};
    *(float4*)&sr[idx] = vr;
    float4 c = *(const float4*)&xi[idx];
    float4 d = *(const float4*)&pi[idx];
    float4 vi = {c.x + d.x, c.y + d.y, c.z + d.z, c.w + d.w};
    *(float4*)&si[idx] = vi;
    float s_r = vr.x + vr.y + vr.z + vr.w;
    float q_r = vr.x*vr.x + vr.y*vr.y + vr.z*vr.z + vr.w*vr.w;
    float s_i = vi.x + vi.y + vi.z + vi.w;
    float q_i = vi.x*vi.x + vi.y*vi.y + vi.z*vi.z + vi.w*vi.w;
    block_stats_commit(s_r, q_r, s_i, q_i, ch, ssum);
}

__global__ __launch_bounds__(256) void addbn_stats_kernel(
    const float* __restrict__ sr, const float* __restrict__ si,
    const float* __restrict__ gr, const float* __restrict__ br,
    const float* __restrict__ gi, const float* __restrict__ bi,
    const float* __restrict__ stats,
    float* __restrict__ mr_, float* __restrict__ mi_,
    float* __restrict__ ssum)
{
    const int ch = blockIdx.x / 36;
    const int pb = blockIdx.x % 36;
    const size_t idx = (size_t)ch * PIX + pb * 1024 + threadIdx.x * 4;
    const float m1r = stats[ch * 2],        i1r = stats[ch * 2 + 1];
    const float m1i = stats[(96 + ch) * 2], i1i = stats[(96 + ch) * 2 + 1];
    const float gr_ = gr[ch], br_ = br[ch], gi_ = gi[ch], bi_ = bi[ch];

    float4 a = *(const float4*)&mr_[idx];
    float4 b = *(const float4*)&sr[idx];
    float4 vr = {a.x + gr_ * (b.x - m1r) * i1r + br_,
                 a.y + gr_ * (b.y - m1r) * i1r + br_,
                 a.z + gr_ * (b.z - m1r) * i1r + br_,
                 a.w + gr_ * (b.w - m1r) * i1r + br_};
    *(float4*)&mr_[idx] = vr;
    float4 c = *(const float4*)&mi_[idx];
    float4 d = *(const float4*)&si[idx];
    float4 vi = {c.x + gi_ * (d.x - m1i) * i1i + bi_,
                 c.y + gi_ * (d.y - m1i) * i1i + bi_,
                 c.z + gi_ * (d.z - m1i) * i1i + bi_,
                 c.w + gi_ * (d.w - m1i) * i1i + bi_};
    *(float4*)&mi_[idx] = vi;
    float s_r = vr.x + vr.y + vr.z + vr.w;
    float q_r = vr.x*vr.x + vr.y*vr.y + vr.z*vr.z + vr.w*vr.w;
    float s_i = vi.x + vi.y + vi.z + vi.w;
    float q_i = vi.x*vi.x + vi.y*vi.y + vi.z*vi.z + vi.w*vi.w;
    block_stats_commit(s_r, q_r, s_i, q_i, ch, ssum);
}

// ======================= final BN apply =======================
__global__ __launch_bounds__(256) void bn_apply_kernel(
    const float* __restrict__ sr, const float* __restrict__ si,
    const float* __restrict__ gr, const float* __restrict__ br,
    const float* __restrict__ gi, const float* __restrict__ bi,
    const float* __restrict__ stats,
    float* __restrict__ outr, float* __restrict__ outi)
{
    int e = blockIdx.x * 256 + threadIdx.x;
    if (e >= 96 * PIX) return;
    int ch = e / PIX;
    float mr = stats[ch * 2],        isr = stats[ch * 2 + 1];
    float mi = stats[(96 + ch) * 2], isi = stats[(96 + ch) * 2 + 1];
    outr[e] = gr[ch] * (sr[e] - mr) * isr + br[ch];
    outi[e] = gi[ch] * (si[e] - mi) * isi + bi[ch];
}

// ======================= launch =======================
extern "C" void kernel_launch(void* const* d_in, const int* in_sizes, int n_in,
                              void* d_out, int out_size, void* d_ws, size_t ws_size,
                              hipStream_t stream)
{
    const float* x_r     = (const float*)d_in[0];
    const float* x_i     = (const float*)d_in[1];
    const float* qkv_wr  = (const float*)d_in[2];
    const float* qkv_wi  = (const float*)d_in[3];
    const float* proj_wr = (const float*)d_in[4];
    const float* proj_wi = (const float*)d_in[5];
    const float* rel     = (const float*)d_in[6];
    const float* mlp1_wr = (const float*)d_in[7];
    const float* mlp1_wi = (const float*)d_in[8];
    const float* mlp2_wr = (const float*)d_in[9];
    const float* mlp2_wi = (const float*)d_in[10];
    const float* n1_gr   = (const float*)d_in[11];
    const float* n1_br   = (const float*)d_in[12];
    const float* n1_gi   = (const float*)d_in[13];
    const float* n1_bi   = (const float*)d_in[14];
    const float* n2_gr   = (const float*)d_in[15];
    const float* n2_br   = (const float*)d_in[16];
    const float* n2_gi   = (const float*)d_in[17];
    const float* n2_bi   = (const float*)d_in[18];

    const size_t P = PIX;
    char* base = (char*)d_ws;

    unsigned short* Dcat = (unsigned short*)base;          // 192*P stacked packed operand
    float* B_r = (float*)(Dcat + 192 * P);                 // s1 fp32 planar
    float* B_i = B_r + 96 * P;
    char*  R   = (char*)(B_i + 96 * P);                    // overlay region
    unsigned short* qkvb = (unsigned short*)R;             // 576*P ushorts
    unsigned short* wout = qkvb + 576 * P;                 // NWIN*32*96*2 ushorts
    float* A_r = (float*)R;                                // proj out / m / s2
    float* A_i = A_r + 96 * P;
    unsigned short* hid = (unsigned short*)(A_i + 96 * P); // 768*P ushorts (stacked hidden)
    unsigned short* Wb = wout + (size_t)NWIN * 32 * 96 * 2;
    unsigned short* Aq = Wb;                    // 576*192 = 110592
    unsigned short* Ap = Aq + 110592;           // 192*192 = 36864
    unsigned short* A1 = Ap + 36864;            // 768*192 = 147456
    unsigned short* A2 = A1 + 147456;           // 192*768 = 147456
    float* stats1 = (float*)(A2 + 147456);
    float* stats2 = stats1 + 384;
    float* ssum1  = stats2 + 384;               // 768 floats zeroed by wconv_all (block 432 zeroes 1536)
    float* ssum2  = ssum1 + 768;

    float* out_r = (float*)d_out;
    float* out_i = out_r + 96 * P;

    dim3 blk(256);

    // 0. build stacked weights + zero stat accumulators (single dispatch)
    wconv_all_kernel<<<dim3(433), blk, 0, stream>>>(
        qkv_wr, qkv_wi, proj_wr, proj_wi, mlp1_wr, mlp1_wi, mlp2_wr, mlp2_wi,
        Aq, Ap, A1, A2, ssum1);

    // 1. pack x -> stacked Dcat (K2=192)
    pack_cat_kernel<<<dim3(144, 24), blk, 0, stream>>>(x_r, x_i, Dcat, PIX);
    // 2. QKV stacked gemm -> qkvb (2M=576, K2=192)
    rgemm_kernel<192, 8, 2, 0><<<dim3(18, 72), blk, 0, stream>>>(
        Aq, Dcat, nullptr, nullptr, qkvb, PIX);
    // 3. MFMA attention -> per-window bf16 outputs
    attn_mfma_kernel<<<dim3((NTASK + 3) / 4), blk, 0, stream>>>(qkvb, rel, wout);
    // 4. fold + /counts + pack (stacked) for proj
    fold_pack_kernel<<<dim3(1728), blk, 0, stream>>>(wout, Dcat);
    // 5. proj stacked gemm -> fp32 planar A (2M=192, K2=192)
    rgemm_kernel<192, 4, 0, 0><<<dim3(6, 144), blk, 0, stream>>>(
        Ap, Dcat, A_r, A_i, nullptr, PIX);
    // 6. s1 = x + proj -> B, BN1 stats
    combine_stats_kernel<<<dim3(3456), blk, 0, stream>>>(x_r, x_i, A_r, A_i, B_r, B_i, ssum1);
    finalize_stats_kernel<<<dim3(1), dim3(192), 0, stream>>>(ssum1, stats1);
    // 7. pack + BN1 apply -> stacked Dcat
    pack_bn_cat_kernel<<<dim3(144, 24), blk, 0, stream>>>(B_r, B_i, stats1,
        n1_gr, n1_br, n1_gi, n1_bi, Dcat, PIX);
    // 8. mlp1 stacked gemm + fused cgelu -> stacked packed hidden (2M=768)
    rgemm_kernel<192, 8, 1, 1><<<dim3(24, 72), blk, 0, stream>>>(
        A1, Dcat, nullptr, nullptr, hid, PIX);
    // 9. mlp2 stacked gemm -> m fp32 planar A (2M=192, K2=768)
    rgemm_kernel<768, 8, 0, 0><<<dim3(6, 72), blk, 0, stream>>>(
        A2, hid, A_r, A_i, nullptr, PIX);
    // 10. s2 = m + bn1(s1), BN2 stats
    addbn_stats_kernel<<<dim3(3456), blk, 0, stream>>>(B_r, B_i,
        n1_gr, n1_br, n1_gi, n1_bi, stats1, A_r, A_i, ssum2);
    finalize_stats_kernel<<<dim3(1), dim3(192), 0, stream>>>(ssum2, stats2);
    // 11. BN2 apply -> out
    bn_apply_kernel<<<dim3(13824), blk, 0, stream>>>(A_r, A_i,
        n2_gr, n2_br, n2_gi, n2_bi, stats2, out_r, out_i);
}

// Round 8
// 388.270 us; speedup vs baseline: 1.0821x; 1.0821x over previous
//
#include <hip/hip_runtime.h>
#include <math.h>

#define PIX 36864          // 192*192
#define IMW 192
#define NWIN 4465          // 47*95
#define NWIN_W 95
#define NTASK (NWIN * 6)

typedef short bf16x8 __attribute__((ext_vector_type(8)));
typedef short bf16x4 __attribute__((ext_vector_type(4)));
typedef float floatx4 __attribute__((ext_vector_type(4)));

#if defined(__has_builtin)
#  if __has_builtin(__builtin_amdgcn_rcpf)
#    define RCP(x) __builtin_amdgcn_rcpf(x)
#  endif
#endif
#ifndef RCP
#  define RCP(x) (1.0f / (x))
#endif

__device__ __forceinline__ unsigned short f2bf(float f) {
    union { float f; unsigned u; } v; v.f = f;
    unsigned r = v.u + 0x7fff + ((v.u >> 16) & 1);   // RNE
    return (unsigned short)(r >> 16);
}
__device__ __forceinline__ float bf2f(unsigned short b) {
    union { unsigned u; float f; } v; v.u = ((unsigned)b) << 16;
    return v.f;
}

// ======================= weight convert =======================
__global__ __launch_bounds__(256) void wconv_kernel(
    const float* __restrict__ wr, const float* __restrict__ wi,
    unsigned short* __restrict__ outr, unsigned short* __restrict__ outi,
    unsigned short* __restrict__ outni, int n)
{
    int e = blockIdx.x * 256 + threadIdx.x;
    if (e >= n) return;
    outr[e] = f2bf(wr[e]);
    unsigned short b = f2bf(wi[e]);
    outi[e]  = b;
    outni[e] = b ^ 0x8000;
}

// ======================= pack: fp32 planar -> bf16 k8-packed =======================
__global__ __launch_bounds__(256) void pack_kernel(
    const float* __restrict__ sr, const float* __restrict__ si,
    unsigned short* __restrict__ dr, unsigned short* __restrict__ di, int N)
{
    int n  = blockIdx.x * 256 + threadIdx.x;
    int kb = blockIdx.y;
    bf16x8 vr, vi;
#pragma unroll
    for (int j = 0; j < 8; ++j) {
        ((unsigned short*)&vr)[j] = f2bf(sr[(size_t)(kb * 8 + j) * N + n]);
        ((unsigned short*)&vi)[j] = f2bf(si[(size_t)(kb * 8 + j) * N + n]);
    }
    *(bf16x8*)&dr[((size_t)kb * N + n) * 8] = vr;
    *(bf16x8*)&di[((size_t)kb * N + n) * 8] = vi;
}

// pack + BN1 apply fused (x1 = bn1(s1) in packed bf16)
__global__ __launch_bounds__(256) void pack_bn_kernel(
    const float* __restrict__ sr, const float* __restrict__ si,
    const float* __restrict__ stats,
    const float* __restrict__ gr, const float* __restrict__ br,
    const float* __restrict__ gi, const float* __restrict__ bi,
    unsigned short* __restrict__ dr, unsigned short* __restrict__ di, int N)
{
    int n  = blockIdx.x * 256 + threadIdx.x;
    int kb = blockIdx.y;
    bf16x8 vr, vi;
#pragma unroll
    for (int j = 0; j < 8; ++j) {
        int ch = kb * 8 + j;
        float mr = stats[ch * 2],        isr = stats[ch * 2 + 1];
        float mi = stats[(96 + ch) * 2], isi = stats[(96 + ch) * 2 + 1];
        ((unsigned short*)&vr)[j] = f2bf(gr[ch] * (sr[(size_t)ch * N + n] - mr) * isr + br[ch]);
        ((unsigned short*)&vi)[j] = f2bf(gi[ch] * (si[(size_t)ch * N + n] - mi) * isi + bi[ch]);
    }
    *(bf16x8*)&dr[((size_t)kb * N + n) * 8] = vr;
    *(bf16x8*)&di[((size_t)kb * N + n) * 8] = vi;
}

// ======================= complex GEMM via MFMA (prefetched K-loop) =======================
// STORE: 0 fp32 planar | 1 k8-packed bf16 (ACT=1: cgelu on acc first) | 2 qkvb slot
// 1D grid, m-fastest decode: blocks sharing a B n-tile are consecutive -> L3 temporal reuse.
template<int K, int MT, int STORE, int ACT>
__global__ __launch_bounds__(256, 2) void cgemm_mfma_kernel(
    const unsigned short* __restrict__ Wr, const unsigned short* __restrict__ Wi,
    const unsigned short* __restrict__ Wni,
    const unsigned short* __restrict__ Xr, const unsigned short* __restrict__ Xi,
    float* __restrict__ Yr, float* __restrict__ Yi,
    unsigned short* __restrict__ Pr, unsigned short* __restrict__ Pi,
    int N)
{
    const int lane = threadIdx.x & 63;
    const int wave = threadIdx.x >> 6;
    const int g = lane >> 4;
    const int r = lane & 15;
    const int m0 = (blockIdx.x % MT) * 32;
    const int n0 = (blockIdx.x / MT) * 256 + wave * 64;

    floatx4 accR[2][4], accI[2][4];
#pragma unroll
    for (int t = 0; t < 2; ++t)
#pragma unroll
        for (int j = 0; j < 4; ++j) {
            accR[t][j] = (floatx4){0.f, 0.f, 0.f, 0.f};
            accI[t][j] = (floatx4){0.f, 0.f, 0.f, 0.f};
        }

    bf16x8 awr[2], awi[2], awni[2], bxr[4], bxi[4];
    auto loadA = [&](int kc, bf16x8* ar, bf16x8* ai, bf16x8* ani) {
#pragma unroll
        for (int t = 0; t < 2; ++t) {
            size_t wb = (size_t)(m0 + t * 16 + r) * K + kc + g * 8;
            ar[t]  = *(const bf16x8*)&Wr[wb];
            ai[t]  = *(const bf16x8*)&Wi[wb];
            ani[t] = *(const bf16x8*)&Wni[wb];
        }
    };
    auto loadB = [&](int kc, bf16x8* br_, bf16x8* bi_) {
        const size_t krow = (size_t)((kc >> 3) + g);
#pragma unroll
        for (int j = 0; j < 4; ++j) {
            size_t off = (krow * N + n0 + j * 16 + r) * 8;
            br_[j] = *(const bf16x8*)&Xr[off];
            bi_[j] = *(const bf16x8*)&Xi[off];
        }
    };

    loadA(0, awr, awi, awni);
    loadB(0, bxr, bxi);

#pragma unroll
    for (int kc = 0; kc < K; kc += 32) {
        bf16x8 nawr[2], nawi[2], nawni[2], nbxr[4], nbxi[4];
        if (kc + 32 < K) {                      // compile-time per unrolled iter
            loadA(kc + 32, nawr, nawi, nawni);
            loadB(kc + 32, nbxr, nbxi);
        }
#pragma unroll
        for (int t = 0; t < 2; ++t)
#pragma unroll
            for (int j = 0; j < 4; ++j) {
                accR[t][j] = __builtin_amdgcn_mfma_f32_16x16x32_bf16(awr[t],  bxr[j], accR[t][j], 0, 0, 0);
                accR[t][j] = __builtin_amdgcn_mfma_f32_16x16x32_bf16(awni[t], bxi[j], accR[t][j], 0, 0, 0);
                accI[t][j] = __builtin_amdgcn_mfma_f32_16x16x32_bf16(awr[t],  bxi[j], accI[t][j], 0, 0, 0);
                accI[t][j] = __builtin_amdgcn_mfma_f32_16x16x32_bf16(awi[t],  bxr[j], accI[t][j], 0, 0, 0);
            }
        if (kc + 32 < K) {
#pragma unroll
            for (int t = 0; t < 2; ++t) { awr[t] = nawr[t]; awi[t] = nawi[t]; awni[t] = nawni[t]; }
#pragma unroll
            for (int j = 0; j < 4; ++j) { bxr[j] = nbxr[j]; bxi[j] = nbxi[j]; }
        }
    }

    if (ACT == 1) {   // cgelu on fp32 accumulators
#pragma unroll
        for (int t = 0; t < 2; ++t)
#pragma unroll
            for (int j = 0; j < 4; ++j)
#pragma unroll
                for (int reg = 0; reg < 4; ++reg) {
                    float a = accR[t][j][reg], b = accI[t][j][reg];
                    float mag = sqrtf(a * a + b * b);
                    float f = (0.5f + 0.5f * erff(mag * 0.70710678118654752f)) * mag * RCP(mag + 1e-8f);
                    accR[t][j][reg] = a * f;
                    accI[t][j][reg] = b * f;
                }
    }

    if (STORE == 0) {
#pragma unroll
        for (int t = 0; t < 2; ++t)
#pragma unroll
            for (int j = 0; j < 4; ++j) {
                int col = n0 + j * 16 + r;
#pragma unroll
                for (int reg = 0; reg < 4; ++reg) {
                    int row = m0 + t * 16 + g * 4 + reg;
                    Yr[(size_t)row * N + col] = accR[t][j][reg];
                    Yi[(size_t)row * N + col] = accI[t][j][reg];
                }
            }
    } else if (STORE == 1) {
#pragma unroll
        for (int t = 0; t < 2; ++t)
#pragma unroll
            for (int j = 0; j < 4; ++j) {
                int col = n0 + j * 16 + r;
                size_t rowblk = (size_t)((m0 + t * 16 + g * 4) >> 3);
                int sub = (g & 1) * 4;
                bf16x4 pr, pi;
#pragma unroll
                for (int reg = 0; reg < 4; ++reg) {
                    ((unsigned short*)&pr)[reg] = f2bf(accR[t][j][reg]);
                    ((unsigned short*)&pi)[reg] = f2bf(accI[t][j][reg]);
                }
                *(bf16x4*)&Pr[(rowblk * N + col) * 8 + sub] = pr;
                *(bf16x4*)&Pi[(rowblk * N + col) * 8 + sub] = pi;
            }
    } else {
#pragma unroll
        for (int t = 0; t < 2; ++t) {
            int ch0 = m0 + t * 16;
            int which = ch0 / 96;
            int hh = (ch0 % 96) / 16;
#pragma unroll
            for (int j = 0; j < 4; ++j) {
                int col = n0 + j * 16 + r;
                bf16x4 pr, pi;
#pragma unroll
                for (int reg = 0; reg < 4; ++reg) {
                    ((unsigned short*)&pr)[reg] = f2bf(accR[t][j][reg]);
                    ((unsigned short*)&pi)[reg] = f2bf(accI[t][j][reg]);
                }
                size_t sb = (((size_t)col * 3 + which) * 6 + hh) * 32;
                *(bf16x4*)&Pr[sb + g * 4]      = pr;
                *(bf16x4*)&Pr[sb + 16 + g * 4] = pi;
            }
        }
    }
}

// ======================= finalize BN stats =======================
__global__ __launch_bounds__(192) void finalize_stats_kernel(
    const float* __restrict__ ssum, float* __restrict__ stats)
{
    int idx = threadIdx.x;
    if (idx >= 192) return;
    float s  = ssum[idx * 2];
    float sq = ssum[idx * 2 + 1];
    float mean = s / (float)PIX;
    float var  = sq / (float)PIX - mean * mean;
    stats[idx * 2]     = mean;
    stats[idx * 2 + 1] = rsqrtf(var + 1e-5f);
}

// ======================= MFMA attention: one wave per (window, head) =======================
__global__ __launch_bounds__(256) void attn_mfma_kernel(
    const unsigned short* __restrict__ qkvb,
    const float* __restrict__ rel,
    unsigned short* __restrict__ wout)
{
    __shared__ unsigned aLDS[4][32 * 36];
    __shared__ unsigned vLDS[4][32 * 17];

    const int wv   = threadIdx.x >> 6;
    const int lane = threadIdx.x & 63;
    const int lr   = lane & 15;
    const int g    = lane >> 4;

    int t = blockIdx.x * 4 + wv;
    if (t >= NTASK) t = NTASK - 1;
    const int w = t / 6, h = t % 6;
    const int nh = w / NWIN_W, nw = w % NWIN_W;
    const int r0 = nh * 4, c0 = nw * 2;

    unsigned* AL = aLDS[wv];
    unsigned* VL = vLDS[wv];

    auto slot = [&](int p, int which) -> size_t {
        int gpix = (r0 + (p >> 2)) * IMW + c0 + (p & 3);
        return ((size_t)gpix * 18 + which * 6 + h) * 32;
    };

    // ---- stage V into LDS as (vr,vi) dword pairs [m][d] ----
    {
        int m = lane & 31;
        int half = lane >> 5;
        size_t sv = slot(m, 2);
        const bf16x8 vr = *(const bf16x8*)&qkvb[sv + half * 8];
        const bf16x8 vi = *(const bf16x8*)&qkvb[sv + 16 + half * 8];
#pragma unroll
        for (int j = 0; j < 8; ++j) {
            unsigned pk = (unsigned)(unsigned short)vr[j] |
                          ((unsigned)(unsigned short)vi[j] << 16);
            VL[m * 17 + half * 8 + j] = pk;
        }
    }

    // ---- Q/K fragments: half-select folded into address, conj via xor ----
    const int hoff = (g >> 1) * 16;
    const int loff = (g & 1) * 8;
    const unsigned sm = (g >= 2) ? 0x80008000u : 0u;
    bf16x8 Are[2], Aim[2], Bre[2], Bim[2];
#pragma unroll
    for (int tt = 0; tt < 2; ++tt) {
        size_t sq = slot(tt * 16 + lr, 0);
        size_t sk = slot(tt * 16 + lr, 1);
        Are[tt] = *(const bf16x8*)&qkvb[sq + hoff + loff];
        Aim[tt] = *(const bf16x8*)&qkvb[sq + (16 - hoff) + loff];
        Bre[tt] = *(const bf16x8*)&qkvb[sk + hoff + loff];
        bf16x8 tmp = Bre[tt];
        unsigned* u = (unsigned*)&tmp;
        u[0] ^= sm; u[1] ^= sm; u[2] ^= sm; u[3] ^= sm;
        Bim[tt] = tmp;
    }

    // ---- S = Q·conj(K)^T : 8 MFMAs ----
    const floatx4 z4 = (floatx4){0.f, 0.f, 0.f, 0.f};
    floatx4 Sre[2][2], Sim[2][2];
#pragma unroll
    for (int tn = 0; tn < 2; ++tn)
#pragma unroll
        for (int tm = 0; tm < 2; ++tm) {
            Sre[tn][tm] = __builtin_amdgcn_mfma_f32_16x16x32_bf16(Are[tn], Bre[tm], z4, 0, 0, 0);
            Sim[tn][tm] = __builtin_amdgcn_mfma_f32_16x16x32_bf16(Aim[tn], Bim[tm], z4, 0, 0, 0);
        }

    // ---- scale + bias, write RAW logits transposed into LDS ----
    const float* relh = rel + h * 105;
#pragma unroll
    for (int tn = 0; tn < 2; ++tn)
#pragma unroll
        for (int tm = 0; tm < 2; ++tm) {
            int m = tm * 16 + lr;
            int ym = m >> 2, xm = m & 3;
            int yn = tn * 4 + g;
            int bidx = (yn - ym + 7) * 7 + (3 - xm);
#pragma unroll
            for (int reg = 0; reg < 4; ++reg) {
                float re = Sre[tn][tm][reg] * 0.25f + relh[bidx + reg];
                float im = Sim[tn][tm][reg] * 0.25f;
                int n = tn * 16 + g * 4 + reg;
                AL[n * 36 + m] = (unsigned)f2bf(re) | ((unsigned)f2bf(im) << 16);
            }
        }
    __syncthreads();

    // ---- row-owner magnitude softmax: 2 lanes per row, 1 shuffle ----
    {
        const int row = lane & 31;
        const int half = lane >> 5;
        unsigned* rp = &AL[row * 36 + half * 16];
        unsigned pk[16];
        *(uint4*)&pk[0]  = *(const uint4*)&rp[0];
        *(uint4*)&pk[4]  = *(const uint4*)&rp[4];
        *(uint4*)&pk[8]  = *(const uint4*)&rp[8];
        *(uint4*)&pk[12] = *(const uint4*)&rp[12];
        float re[16], im[16], mg[16];
#pragma unroll
        for (int j = 0; j < 16; ++j) {
            union { unsigned u; float f; } a, b;
            a.u = pk[j] << 16;
            b.u = pk[j] & 0xffff0000u;
            re[j] = a.f; im[j] = b.f;
            mg[j] = sqrtf(a.f * a.f + b.f * b.f);
        }
        float mx = mg[0];
#pragma unroll
        for (int j = 1; j < 16; ++j) mx = fmaxf(mx, mg[j]);
        mx = fmaxf(mx, __shfl_xor(mx, 32, 64));
        float es[16], ss = 0.f;
#pragma unroll
        for (int j = 0; j < 16; ++j) { es[j] = __expf(mg[j] - mx); ss += es[j]; }
        ss += __shfl_xor(ss, 32, 64);
        float inv = RCP(ss);
#pragma unroll
        for (int j = 0; j < 16; ++j) {
            float f = es[j] * inv * RCP(mg[j] + 1e-8f);
            pk[j] = (unsigned)f2bf(re[j] * f) | ((unsigned)f2bf(im[j] * f) << 16);
        }
        *(uint4*)&rp[0]  = *(uint4*)&pk[0];
        *(uint4*)&rp[4]  = *(uint4*)&pk[4];
        *(uint4*)&rp[8]  = *(uint4*)&pk[8];
        *(uint4*)&rp[12] = *(uint4*)&pk[12];
    }
    __syncthreads();

    // ---- P = attn · V : 8 MFMAs ----
    floatx4 Pre[2] = {z4, z4}, Pim[2] = {z4, z4};
#pragma unroll
    for (int kc = 0; kc < 2; ++kc) {
        bf16x8 Bpr, Bpi;
        unsigned* bpr = (unsigned*)&Bpr;
        unsigned* bpi = (unsigned*)&Bpi;
#pragma unroll
        for (int p = 0; p < 4; ++p) {
            unsigned pv = VL[(kc * 16 + g * 4 + p) * 17 + lr];
            bpr[p] = pv ^ 0x80000000u;
            bpi[p] = (pv >> 16) | (pv << 16);
        }
#pragma unroll
        for (int tn = 0; tn < 2; ++tn) {
            bf16x8 Af = *(bf16x8*)&AL[(tn * 16 + lr) * 36 + kc * 16 + g * 4];
            Pre[tn] = __builtin_amdgcn_mfma_f32_16x16x32_bf16(Af, Bpr, Pre[tn], 0, 0, 0);
            Pim[tn] = __builtin_amdgcn_mfma_f32_16x16x32_bf16(Af, Bpi, Pim[tn], 0, 0, 0);
        }
    }

    // ---- epilogue ----
#pragma unroll
    for (int tn = 0; tn < 2; ++tn)
#pragma unroll
        for (int reg = 0; reg < 4; ++reg) {
            int n = tn * 16 + g * 4 + reg;
            int ch = h * 16 + lr;
            unsigned pk = (unsigned)f2bf(Pre[tn][reg]) |
                          ((unsigned)f2bf(Pim[tn][reg]) << 16);
            *(unsigned*)&wout[(((size_t)w * 32 + n) * 96 + ch) * 2] = pk;
        }
}

// ======================= fold + count-div + pack for proj =======================
__global__ __launch_bounds__(256) void fold_pack_kernel(
    const unsigned short* __restrict__ wout,
    unsigned short* __restrict__ dr, unsigned short* __restrict__ di)
{
    int e = blockIdx.x * 256 + threadIdx.x;   // PIX*12
    int gpix = e / 12;
    int kb   = e % 12;
    int r = gpix / IMW, c = gpix % IMW;
    int nh0 = (r >= 7) ? ((r - 4) >> 2) : 0;
    int nh1 = min(46, r >> 2);
    int nw0 = (c >= 3) ? ((c - 2) >> 1) : 0;
    int nw1 = min(94, c >> 1);

    float accr[8] = {0,0,0,0,0,0,0,0}, acci[8] = {0,0,0,0,0,0,0,0};
    int cnt = 0;
    for (int nh = nh0; nh <= nh1; ++nh)
        for (int nw = nw0; nw <= nw1; ++nw) {
            int win = nh * NWIN_W + nw;
            int n = (r - nh * 4) * 4 + (c - nw * 2);
            const unsigned short* src = &wout[(((size_t)win * 32 + n) * 96 + kb * 8) * 2];
            bf16x8 a = *(const bf16x8*)&src[0];
            bf16x8 b = *(const bf16x8*)&src[8];
#pragma unroll
            for (int j = 0; j < 4; ++j) {
                accr[j]     += bf2f((unsigned short)a[j*2]);
                acci[j]     += bf2f((unsigned short)a[j*2+1]);
                accr[4 + j] += bf2f((unsigned short)b[j*2]);
                acci[4 + j] += bf2f((unsigned short)b[j*2+1]);
            }
            ++cnt;
        }
    float invc = 1.0f / ((float)cnt + 1e-8f);
    bf16x8 pr, pi;
#pragma unroll
    for (int j = 0; j < 8; ++j) {
        ((unsigned short*)&pr)[j] = f2bf(accr[j] * invc);
        ((unsigned short*)&pi)[j] = f2bf(acci[j] * invc);
    }
    *(bf16x8*)&dr[((size_t)kb * PIX + gpix) * 8] = pr;
    *(bf16x8*)&di[((size_t)kb * PIX + gpix) * 8] = pi;
}

// ======================= fused elementwise + BN-stat kernels =======================
__device__ __forceinline__ void block_stats_commit(
    float s_r, float q_r, float s_i, float q_i, int ch, float* __restrict__ ssum)
{
#pragma unroll
    for (int msk = 1; msk < 64; msk <<= 1) {
        s_r += __shfl_xor(s_r, msk, 64);
        q_r += __shfl_xor(q_r, msk, 64);
        s_i += __shfl_xor(s_i, msk, 64);
        q_i += __shfl_xor(q_i, msk, 64);
    }
    __shared__ float red[4][4];
    const int wv = threadIdx.x >> 6;
    if ((threadIdx.x & 63) == 0) {
        red[wv][0] = s_r; red[wv][1] = q_r; red[wv][2] = s_i; red[wv][3] = q_i;
    }
    __syncthreads();
    if (threadIdx.x == 0) {
        float a0 = red[0][0] + red[1][0] + red[2][0] + red[3][0];
        float a1 = red[0][1] + red[1][1] + red[2][1] + red[3][1];
        float a2 = red[0][2] + red[1][2] + red[2][2] + red[3][2];
        float a3 = red[0][3] + red[1][3] + red[2][3] + red[3][3];
        atomicAdd(&ssum[ch * 2],            a0);
        atomicAdd(&ssum[ch * 2 + 1],        a1);
        atomicAdd(&ssum[(96 + ch) * 2],     a2);
        atomicAdd(&ssum[(96 + ch) * 2 + 1], a3);
    }
}

__global__ __launch_bounds__(256) void combine_stats_kernel(
    const float* __restrict__ xr, const float* __restrict__ xi,
    const float* __restrict__ pr, const float* __restrict__ pi,
    float* __restrict__ sr, float* __restrict__ si,
    float* __restrict__ ssum)
{
    const int ch = blockIdx.x / 36;
    const int pb = blockIdx.x % 36;
    const size_t idx = (size_t)ch * PIX + pb * 1024 + threadIdx.x * 4;
    float4 a = *(const float4*)&xr[idx];
    float4 b = *(const float4*)&pr[idx];
    float4 vr = {a.x + b.x, a.y + b.y, a.z + b.z, a.w + b.w};
    *(float4*)&sr[idx] = vr;
    float4 c = *(const float4*)&xi[idx];
    float4 d = *(const float4*)&pi[idx];
    float4 vi = {c.x + d.x, c.y + d.y, c.z + d.z, c.w + d.w};
    *(float4*)&si[idx] = vi;
    float s_r = vr.x + vr.y + vr.z + vr.w;
    float q_r = vr.x*vr.x + vr.y*vr.y + vr.z*vr.z + vr.w*vr.w;
    float s_i = vi.x + vi.y + vi.z + vi.w;
    float q_i = vi.x*vi.x + vi.y*vi.y + vi.z*vi.z + vi.w*vi.w;
    block_stats_commit(s_r, q_r, s_i, q_i, ch, ssum);
}

__global__ __launch_bounds__(256) void addbn_stats_kernel(
    const float* __restrict__ sr, const float* __restrict__ si,
    const float* __restrict__ gr, const float* __restrict__ br,
    const float* __restrict__ gi, const float* __restrict__ bi,
    const float* __restrict__ stats,
    float* __restrict__ mr_, float* __restrict__ mi_,
    float* __restrict__ ssum)
{
    const int ch = blockIdx.x / 36;
    const int pb = blockIdx.x % 36;
    const size_t idx = (size_t)ch * PIX + pb * 1024 + threadIdx.x * 4;
    const float m1r = stats[ch * 2],        i1r = stats[ch * 2 + 1];
    const float m1i = stats[(96 + ch) * 2], i1i = stats[(96 + ch) * 2 + 1];
    const float gr_ = gr[ch], br_ = br[ch], gi_ = gi[ch], bi_ = bi[ch];

    float4 a = *(const float4*)&mr_[idx];
    float4 b = *(const float4*)&sr[idx];
    float4 vr = {a.x + gr_ * (b.x - m1r) * i1r + br_,
                 a.y + gr_ * (b.y - m1r) * i1r + br_,
                 a.z + gr_ * (b.z - m1r) * i1r + br_,
                 a.w + gr_ * (b.w - m1r) * i1r + br_};
    *(float4*)&mr_[idx] = vr;
    float4 c = *(const float4*)&mi_[idx];
    float4 d = *(const float4*)&si[idx];
    float4 vi = {c.x + gi_ * (d.x - m1i) * i1i + bi_,
                 c.y + gi_ * (d.y - m1i) * i1i + bi_,
                 c.z + gi_ * (d.z - m1i) * i1i + bi_,
                 c.w + gi_ * (d.w - m1i) * i1i + bi_};
    *(float4*)&mi_[idx] = vi;
    float s_r = vr.x + vr.y + vr.z + vr.w;
    float q_r = vr.x*vr.x + vr.y*vr.y + vr.z*vr.z + vr.w*vr.w;
    float s_i = vi.x + vi.y + vi.z + vi.w;
    float q_i = vi.x*vi.x + vi.y*vi.y + vi.z*vi.z + vi.w*vi.w;
    block_stats_commit(s_r, q_r, s_i, q_i, ch, ssum);
}

// ======================= final BN apply =======================
__global__ __launch_bounds__(256) void bn_apply_kernel(
    const float* __restrict__ sr, const float* __restrict__ si,
    const float* __restrict__ gr, const float* __restrict__ br,
    const float* __restrict__ gi, const float* __restrict__ bi,
    const float* __restrict__ stats,
    float* __restrict__ outr, float* __restrict__ outi)
{
    int e = blockIdx.x * 256 + threadIdx.x;
    if (e >= 96 * PIX) return;
    int ch = e / PIX;
    float mr = stats[ch * 2],        isr = stats[ch * 2 + 1];
    float mi = stats[(96 + ch) * 2], isi = stats[(96 + ch) * 2 + 1];
    outr[e] = gr[ch] * (sr[e] - mr) * isr + br[ch];
    outi[e] = gi[ch] * (si[e] - mi) * isi + bi[ch];
}

// ======================= launch =======================
extern "C" void kernel_launch(void* const* d_in, const int* in_sizes, int n_in,
                              void* d_out, int out_size, void* d_ws, size_t ws_size,
                              hipStream_t stream)
{
    const float* x_r     = (const float*)d_in[0];
    const float* x_i     = (const float*)d_in[1];
    const float* qkv_wr  = (const float*)d_in[2];
    const float* qkv_wi  = (const float*)d_in[3];
    const float* proj_wr = (const float*)d_in[4];
    const float* proj_wi = (const float*)d_in[5];
    const float* rel     = (const float*)d_in[6];
    const float* mlp1_wr = (const float*)d_in[7];
    const float* mlp1_wi = (const float*)d_in[8];
    const float* mlp2_wr = (const float*)d_in[9];
    const float* mlp2_wi = (const float*)d_in[10];
    const float* n1_gr   = (const float*)d_in[11];
    const float* n1_br   = (const float*)d_in[12];
    const float* n1_gi   = (const float*)d_in[13];
    const float* n1_bi   = (const float*)d_in[14];
    const float* n2_gr   = (const float*)d_in[15];
    const float* n2_br   = (const float*)d_in[16];
    const float* n2_gi   = (const float*)d_in[17];
    const float* n2_bi   = (const float*)d_in[18];

    const size_t P = PIX;
    char* base = (char*)d_ws;

    unsigned short* Dr = (unsigned short*)base;           // 96*P packed operand
    unsigned short* Di = Dr + 96 * P;
    float* B_r = (float*)(Di + 96 * P);                   // s1 fp32 planar
    float* B_i = B_r + 96 * P;
    char*  R   = (char*)(B_i + 96 * P);                   // overlay region
    unsigned short* qkvb = (unsigned short*)R;            // 576*P ushorts
    unsigned short* wout = qkvb + 576 * P;                // NWIN*32*96*2 ushorts
    float* A_r = (float*)R;                               // proj out / m / s2
    float* A_i = A_r + 96 * P;
    unsigned short* hid_r = (unsigned short*)(A_i + 96 * P);   // 384*P packed hidden
    unsigned short* hid_i = hid_r + 384 * P;
    unsigned short* Wb = wout + (size_t)NWIN * 32 * 96 * 2;    // weights bf16
    float* stats1 = (float*)(Wb + 331776);
    float* stats2 = stats1 + 384;
    float* ssum1  = stats2 + 384;
    float* ssum2  = ssum1 + 384;

    unsigned short* wq_r  = Wb;            unsigned short* wq_i  = Wb + 27648;  unsigned short* wq_ni = Wb + 55296;
    unsigned short* wp_r  = Wb + 82944;    unsigned short* wp_i  = Wb + 92160;  unsigned short* wp_ni = Wb + 101376;
    unsigned short* w1_r  = Wb + 110592;   unsigned short* w1_i  = Wb + 147456; unsigned short* w1_ni = Wb + 184320;
    unsigned short* w2_r  = Wb + 221184;   unsigned short* w2_i  = Wb + 258048; unsigned short* w2_ni = Wb + 294912;

    float* out_r = (float*)d_out;
    float* out_i = out_r + 96 * P;

    dim3 blk(256);

    // 0. zero BN stat accumulators (ssum1+ssum2); weights -> bf16
    hipMemsetAsync(ssum1, 0, 768 * sizeof(float), stream);
    wconv_kernel<<<dim3(108), blk, 0, stream>>>(qkv_wr, qkv_wi, wq_r, wq_i, wq_ni, 27648);
    wconv_kernel<<<dim3(36),  blk, 0, stream>>>(proj_wr, proj_wi, wp_r, wp_i, wp_ni, 9216);
    wconv_kernel<<<dim3(144), blk, 0, stream>>>(mlp1_wr, mlp1_wi, w1_r, w1_i, w1_ni, 36864);
    wconv_kernel<<<dim3(144), blk, 0, stream>>>(mlp2_wr, mlp2_wi, w2_r, w2_i, w2_ni, 36864);

    // 1. pack x
    pack_kernel<<<dim3(144, 12), blk, 0, stream>>>(x_r, x_i, Dr, Di, PIX);
    // 2. QKV gemm -> comp-planar pixel-major qkvb  (MT=9, 1D m-fast grid)
    cgemm_mfma_kernel<96, 9, 2, 0><<<dim3(9 * 144), blk, 0, stream>>>(
        wq_r, wq_i, wq_ni, Dr, Di, nullptr, nullptr, qkvb, nullptr, PIX);
    // 3. MFMA attention -> per-window bf16 outputs
    attn_mfma_kernel<<<dim3((NTASK + 3) / 4), blk, 0, stream>>>(qkvb, rel, wout);
    // 4. fold + /counts + pack for proj
    fold_pack_kernel<<<dim3(1728), blk, 0, stream>>>(wout, Dr, Di);
    // 5. proj gemm -> fp32 planar A  (MT=3)
    cgemm_mfma_kernel<96, 3, 0, 0><<<dim3(3 * 144), blk, 0, stream>>>(
        wp_r, wp_i, wp_ni, Dr, Di, A_r, A_i, nullptr, nullptr, PIX);
    // 6. s1 = x + proj -> B, BN1 stats accumulated
    combine_stats_kernel<<<dim3(3456), blk, 0, stream>>>(x_r, x_i, A_r, A_i, B_r, B_i, ssum1);
    finalize_stats_kernel<<<dim3(1), dim3(192), 0, stream>>>(ssum1, stats1);
    // 7. pack + BN1 apply -> packed x1
    pack_bn_kernel<<<dim3(144, 12), blk, 0, stream>>>(B_r, B_i, stats1,
        n1_gr, n1_br, n1_gi, n1_bi, Dr, Di, PIX);
    // 8. mlp1 gemm + fused cgelu -> packed bf16 hidden  (MT=12)
    cgemm_mfma_kernel<96, 12, 1, 1><<<dim3(12 * 144), blk, 0, stream>>>(
        w1_r, w1_i, w1_ni, Dr, Di, nullptr, nullptr, hid_r, hid_i, PIX);
    // 9. mlp2 gemm -> m (fp32 planar A)  (MT=3, K=384)
    cgemm_mfma_kernel<384, 3, 0, 0><<<dim3(3 * 144), blk, 0, stream>>>(
        w2_r, w2_i, w2_ni, hid_r, hid_i, A_r, A_i, nullptr, nullptr, PIX);
    // 10. s2 = m + bn1(s1) in place on A, BN2 stats accumulated
    addbn_stats_kernel<<<dim3(3456), blk, 0, stream>>>(B_r, B_i,
        n1_gr, n1_br, n1_gi, n1_bi, stats1, A_r, A_i, ssum2);
    finalize_stats_kernel<<<dim3(1), dim3(192), 0, stream>>>(ssum2, stats2);
    // 11. BN2 apply -> out
    bn_apply_kernel<<<dim3(13824), blk, 0, stream>>>(A_r, A_i,
        n2_gr, n2_br, n2_gi, n2_bi, stats2, out_r, out_i);
}

// Round 9
// 346.423 us; speedup vs baseline: 1.2128x; 1.1208x over previous
//
#include <hip/hip_runtime.h>
#include <math.h>

#define PIX 36864          // 192*192
#define IMW 192
#define NWIN 4465          // 47*95
#define NWIN_W 95
#define NTASK (NWIN * 6)

typedef short bf16x8 __attribute__((ext_vector_type(8)));
typedef short bf16x4 __attribute__((ext_vector_type(4)));
typedef float floatx4 __attribute__((ext_vector_type(4)));

#if defined(__has_builtin)
#  if __has_builtin(__builtin_amdgcn_rcpf)
#    define RCP(x) __builtin_amdgcn_rcpf(x)
#  endif
#endif
#ifndef RCP
#  define RCP(x) (1.0f / (x))
#endif

__device__ __forceinline__ unsigned short f2bf(float f) {
    union { float f; unsigned u; } v; v.f = f;
    unsigned r = v.u + 0x7fff + ((v.u >> 16) & 1);   // RNE
    return (unsigned short)(r >> 16);
}
__device__ __forceinline__ float bf2f(unsigned short b) {
    union { unsigned u; float f; } v; v.u = ((unsigned)b) << 16;
    return v.f;
}

// ======================= weight convert (qkv/proj/mlp2) + ssum zero, ONE dispatch =======================
__device__ __forceinline__ void emit3(
    const float* __restrict__ wr, const float* __restrict__ wi,
    unsigned short* __restrict__ outr, unsigned short* __restrict__ outi,
    unsigned short* __restrict__ outni, int e)
{
    outr[e] = f2bf(wr[e]);
    unsigned short b = f2bf(wi[e]);
    outi[e]  = b;
    outni[e] = b ^ 0x8000;
}

__global__ __launch_bounds__(256) void wconv_all_kernel(
    const float* __restrict__ qwr, const float* __restrict__ qwi,
    const float* __restrict__ pwr, const float* __restrict__ pwi,
    const float* __restrict__ w2r, const float* __restrict__ w2i,
    unsigned short* __restrict__ wq, unsigned short* __restrict__ wp,
    unsigned short* __restrict__ w2, float* __restrict__ ssum)
{
    int blk = blockIdx.x;
    if (blk == 288) {
        for (int j = threadIdx.x; j < 768; j += 256) ssum[j] = 0.f;
        return;
    }
    if (blk < 108)      emit3(qwr, qwi, wq, wq + 27648, wq + 55296, blk * 256 + threadIdx.x);
    else if (blk < 144) emit3(pwr, pwi, wp, wp + 9216,  wp + 18432, (blk - 108) * 256 + threadIdx.x);
    else                emit3(w2r, w2i, w2, w2 + 36864, w2 + 73728, (blk - 144) * 256 + threadIdx.x);
}

// ======================= pack: fp32 planar -> bf16 k8-packed =======================
__global__ __launch_bounds__(256) void pack_kernel(
    const float* __restrict__ sr, const float* __restrict__ si,
    unsigned short* __restrict__ dr, unsigned short* __restrict__ di, int N)
{
    int n  = blockIdx.x * 256 + threadIdx.x;
    int kb = blockIdx.y;
    bf16x8 vr, vi;
#pragma unroll
    for (int j = 0; j < 8; ++j) {
        ((unsigned short*)&vr)[j] = f2bf(sr[(size_t)(kb * 8 + j) * N + n]);
        ((unsigned short*)&vi)[j] = f2bf(si[(size_t)(kb * 8 + j) * N + n]);
    }
    *(bf16x8*)&dr[((size_t)kb * N + n) * 8] = vr;
    *(bf16x8*)&di[((size_t)kb * N + n) * 8] = vi;
}

// ======================= complex GEMM via MFMA (round-8 proven form) =======================
// STORE: 0 fp32 planar | 2 qkvb pixel-major slot
template<int K, int MT, int STORE>
__global__ __launch_bounds__(256, 2) void cgemm_mfma_kernel(
    const unsigned short* __restrict__ Wr, const unsigned short* __restrict__ Wi,
    const unsigned short* __restrict__ Wni,
    const unsigned short* __restrict__ Xr, const unsigned short* __restrict__ Xi,
    float* __restrict__ Yr, float* __restrict__ Yi,
    unsigned short* __restrict__ Pr, int N)
{
    const int lane = threadIdx.x & 63;
    const int wave = threadIdx.x >> 6;
    const int g = lane >> 4;
    const int r = lane & 15;
    const int m0 = (blockIdx.x % MT) * 32;
    const int n0 = (blockIdx.x / MT) * 256 + wave * 64;

    floatx4 accR[2][4], accI[2][4];
#pragma unroll
    for (int t = 0; t < 2; ++t)
#pragma unroll
        for (int j = 0; j < 4; ++j) {
            accR[t][j] = (floatx4){0.f, 0.f, 0.f, 0.f};
            accI[t][j] = (floatx4){0.f, 0.f, 0.f, 0.f};
        }

    for (int kc = 0; kc < K; kc += 32) {
        bf16x8 awr[2], awi[2], awni[2];
#pragma unroll
        for (int t = 0; t < 2; ++t) {
            size_t wb = (size_t)(m0 + t * 16 + r) * K + kc + g * 8;
            awr[t]  = *(const bf16x8*)&Wr[wb];
            awi[t]  = *(const bf16x8*)&Wi[wb];
            awni[t] = *(const bf16x8*)&Wni[wb];
        }
        bf16x8 bxr[4], bxi[4];
        const size_t krow = (size_t)((kc >> 3) + g);
#pragma unroll
        for (int j = 0; j < 4; ++j) {
            size_t off = (krow * N + n0 + j * 16 + r) * 8;
            bxr[j] = *(const bf16x8*)&Xr[off];
            bxi[j] = *(const bf16x8*)&Xi[off];
        }
#pragma unroll
        for (int t = 0; t < 2; ++t)
#pragma unroll
            for (int j = 0; j < 4; ++j) {
                accR[t][j] = __builtin_amdgcn_mfma_f32_16x16x32_bf16(awr[t],  bxr[j], accR[t][j], 0, 0, 0);
                accR[t][j] = __builtin_amdgcn_mfma_f32_16x16x32_bf16(awni[t], bxi[j], accR[t][j], 0, 0, 0);
                accI[t][j] = __builtin_amdgcn_mfma_f32_16x16x32_bf16(awr[t],  bxi[j], accI[t][j], 0, 0, 0);
                accI[t][j] = __builtin_amdgcn_mfma_f32_16x16x32_bf16(awi[t],  bxr[j], accI[t][j], 0, 0, 0);
            }
    }

    if (STORE == 0) {
#pragma unroll
        for (int t = 0; t < 2; ++t)
#pragma unroll
            for (int j = 0; j < 4; ++j) {
                int col = n0 + j * 16 + r;
#pragma unroll
                for (int reg = 0; reg < 4; ++reg) {
                    int row = m0 + t * 16 + g * 4 + reg;
                    Yr[(size_t)row * N + col] = accR[t][j][reg];
                    Yi[(size_t)row * N + col] = accI[t][j][reg];
                }
            }
    } else {
#pragma unroll
        for (int t = 0; t < 2; ++t) {
            int ch0 = m0 + t * 16;
            int which = ch0 / 96;
            int hh = (ch0 % 96) / 16;
#pragma unroll
            for (int j = 0; j < 4; ++j) {
                int col = n0 + j * 16 + r;
                bf16x4 pr, pi;
#pragma unroll
                for (int reg = 0; reg < 4; ++reg) {
                    ((unsigned short*)&pr)[reg] = f2bf(accR[t][j][reg]);
                    ((unsigned short*)&pi)[reg] = f2bf(accI[t][j][reg]);
                }
                size_t sb = (((size_t)col * 3 + which) * 6 + hh) * 32;
                *(bf16x4*)&Pr[sb + g * 4]      = pr;
                *(bf16x4*)&Pr[sb + 16 + g * 4] = pi;
            }
        }
    }
}

// ======================= MFMA attention (unchanged, proven 56 us) =======================
__global__ __launch_bounds__(256) void attn_mfma_kernel(
    const unsigned short* __restrict__ qkvb,
    const float* __restrict__ rel,
    unsigned short* __restrict__ wout)
{
    __shared__ unsigned aLDS[4][32 * 36];
    __shared__ unsigned vLDS[4][32 * 17];

    const int wv   = threadIdx.x >> 6;
    const int lane = threadIdx.x & 63;
    const int lr   = lane & 15;
    const int g    = lane >> 4;

    int t = blockIdx.x * 4 + wv;
    if (t >= NTASK) t = NTASK - 1;
    const int w = t / 6, h = t % 6;
    const int nh = w / NWIN_W, nw = w % NWIN_W;
    const int r0 = nh * 4, c0 = nw * 2;

    unsigned* AL = aLDS[wv];
    unsigned* VL = vLDS[wv];

    auto slot = [&](int p, int which) -> size_t {
        int gpix = (r0 + (p >> 2)) * IMW + c0 + (p & 3);
        return ((size_t)gpix * 18 + which * 6 + h) * 32;
    };

    {
        int m = lane & 31;
        int half = lane >> 5;
        size_t sv = slot(m, 2);
        const bf16x8 vr = *(const bf16x8*)&qkvb[sv + half * 8];
        const bf16x8 vi = *(const bf16x8*)&qkvb[sv + 16 + half * 8];
#pragma unroll
        for (int j = 0; j < 8; ++j) {
            unsigned pk = (unsigned)(unsigned short)vr[j] |
                          ((unsigned)(unsigned short)vi[j] << 16);
            VL[m * 17 + half * 8 + j] = pk;
        }
    }

    const int hoff = (g >> 1) * 16;
    const int loff = (g & 1) * 8;
    const unsigned sm = (g >= 2) ? 0x80008000u : 0u;
    bf16x8 Are[2], Aim[2], Bre[2], Bim[2];
#pragma unroll
    for (int tt = 0; tt < 2; ++tt) {
        size_t sq = slot(tt * 16 + lr, 0);
        size_t sk = slot(tt * 16 + lr, 1);
        Are[tt] = *(const bf16x8*)&qkvb[sq + hoff + loff];
        Aim[tt] = *(const bf16x8*)&qkvb[sq + (16 - hoff) + loff];
        Bre[tt] = *(const bf16x8*)&qkvb[sk + hoff + loff];
        bf16x8 tmp = Bre[tt];
        unsigned* u = (unsigned*)&tmp;
        u[0] ^= sm; u[1] ^= sm; u[2] ^= sm; u[3] ^= sm;
        Bim[tt] = tmp;
    }

    const floatx4 z4 = (floatx4){0.f, 0.f, 0.f, 0.f};
    floatx4 Sre[2][2], Sim[2][2];
#pragma unroll
    for (int tn = 0; tn < 2; ++tn)
#pragma unroll
        for (int tm = 0; tm < 2; ++tm) {
            Sre[tn][tm] = __builtin_amdgcn_mfma_f32_16x16x32_bf16(Are[tn], Bre[tm], z4, 0, 0, 0);
            Sim[tn][tm] = __builtin_amdgcn_mfma_f32_16x16x32_bf16(Aim[tn], Bim[tm], z4, 0, 0, 0);
        }

    const float* relh = rel + h * 105;
#pragma unroll
    for (int tn = 0; tn < 2; ++tn)
#pragma unroll
        for (int tm = 0; tm < 2; ++tm) {
            int m = tm * 16 + lr;
            int ym = m >> 2, xm = m & 3;
            int yn = tn * 4 + g;
            int bidx = (yn - ym + 7) * 7 + (3 - xm);
#pragma unroll
            for (int reg = 0; reg < 4; ++reg) {
                float re = Sre[tn][tm][reg] * 0.25f + relh[bidx + reg];
                float im = Sim[tn][tm][reg] * 0.25f;
                int n = tn * 16 + g * 4 + reg;
                AL[n * 36 + m] = (unsigned)f2bf(re) | ((unsigned)f2bf(im) << 16);
            }
        }
    __syncthreads();

    {
        const int row = lane & 31;
        const int half = lane >> 5;
        unsigned* rp = &AL[row * 36 + half * 16];
        unsigned pk[16];
        *(uint4*)&pk[0]  = *(const uint4*)&rp[0];
        *(uint4*)&pk[4]  = *(const uint4*)&rp[4];
        *(uint4*)&pk[8]  = *(const uint4*)&rp[8];
        *(uint4*)&pk[12] = *(const uint4*)&rp[12];
        float re[16], im[16], mg[16];
#pragma unroll
        for (int j = 0; j < 16; ++j) {
            union { unsigned u; float f; } a, b;
            a.u = pk[j] << 16;
            b.u = pk[j] & 0xffff0000u;
            re[j] = a.f; im[j] = b.f;
            mg[j] = sqrtf(a.f * a.f + b.f * b.f);
        }
        float mx = mg[0];
#pragma unroll
        for (int j = 1; j < 16; ++j) mx = fmaxf(mx, mg[j]);
        mx = fmaxf(mx, __shfl_xor(mx, 32, 64));
        float es[16], ss = 0.f;
#pragma unroll
        for (int j = 0; j < 16; ++j) { es[j] = __expf(mg[j] - mx); ss += es[j]; }
        ss += __shfl_xor(ss, 32, 64);
        float inv = RCP(ss);
#pragma unroll
        for (int j = 0; j < 16; ++j) {
            float f = es[j] * inv * RCP(mg[j] + 1e-8f);
            pk[j] = (unsigned)f2bf(re[j] * f) | ((unsigned)f2bf(im[j] * f) << 16);
        }
        *(uint4*)&rp[0]  = *(uint4*)&pk[0];
        *(uint4*)&rp[4]  = *(uint4*)&pk[4];
        *(uint4*)&rp[8]  = *(uint4*)&pk[8];
        *(uint4*)&rp[12] = *(uint4*)&pk[12];
    }
    __syncthreads();

    floatx4 Pre[2] = {z4, z4}, Pim[2] = {z4, z4};
#pragma unroll
    for (int kc = 0; kc < 2; ++kc) {
        bf16x8 Bpr, Bpi;
        unsigned* bpr = (unsigned*)&Bpr;
        unsigned* bpi = (unsigned*)&Bpi;
#pragma unroll
        for (int p = 0; p < 4; ++p) {
            unsigned pv = VL[(kc * 16 + g * 4 + p) * 17 + lr];
            bpr[p] = pv ^ 0x80000000u;
            bpi[p] = (pv >> 16) | (pv << 16);
        }
#pragma unroll
        for (int tn = 0; tn < 2; ++tn) {
            bf16x8 Af = *(bf16x8*)&AL[(tn * 16 + lr) * 36 + kc * 16 + g * 4];
            Pre[tn] = __builtin_amdgcn_mfma_f32_16x16x32_bf16(Af, Bpr, Pre[tn], 0, 0, 0);
            Pim[tn] = __builtin_amdgcn_mfma_f32_16x16x32_bf16(Af, Bpi, Pim[tn], 0, 0, 0);
        }
    }

#pragma unroll
    for (int tn = 0; tn < 2; ++tn)
#pragma unroll
        for (int reg = 0; reg < 4; ++reg) {
            int n = tn * 16 + g * 4 + reg;
            int ch = h * 16 + lr;
            unsigned pk = (unsigned)f2bf(Pre[tn][reg]) |
                          ((unsigned)f2bf(Pim[tn][reg]) << 16);
            *(unsigned*)&wout[(((size_t)w * 32 + n) * 96 + ch) * 2] = pk;
        }
}

// ======================= fold + count-div + pack for proj (unchanged) =======================
__global__ __launch_bounds__(256) void fold_pack_kernel(
    const unsigned short* __restrict__ wout,
    unsigned short* __restrict__ dr, unsigned short* __restrict__ di)
{
    int e = blockIdx.x * 256 + threadIdx.x;   // PIX*12
    int gpix = e / 12;
    int kb   = e % 12;
    int r = gpix / IMW, c = gpix % IMW;
    int nh0 = (r >= 7) ? ((r - 4) >> 2) : 0;
    int nh1 = min(46, r >> 2);
    int nw0 = (c >= 3) ? ((c - 2) >> 1) : 0;
    int nw1 = min(94, c >> 1);

    float accr[8] = {0,0,0,0,0,0,0,0}, acci[8] = {0,0,0,0,0,0,0,0};
    int cnt = 0;
    for (int nh = nh0; nh <= nh1; ++nh)
        for (int nw = nw0; nw <= nw1; ++nw) {
            int win = nh * NWIN_W + nw;
            int n = (r - nh * 4) * 4 + (c - nw * 2);
            const unsigned short* src = &wout[(((size_t)win * 32 + n) * 96 + kb * 8) * 2];
            bf16x8 a = *(const bf16x8*)&src[0];
            bf16x8 b = *(const bf16x8*)&src[8];
#pragma unroll
            for (int j = 0; j < 4; ++j) {
                accr[j]     += bf2f((unsigned short)a[j*2]);
                acci[j]     += bf2f((unsigned short)a[j*2+1]);
                accr[4 + j] += bf2f((unsigned short)b[j*2]);
                acci[4 + j] += bf2f((unsigned short)b[j*2+1]);
            }
            ++cnt;
        }
    float invc = 1.0f / ((float)cnt + 1e-8f);
    bf16x8 pr, pi;
#pragma unroll
    for (int j = 0; j < 8; ++j) {
        ((unsigned short*)&pr)[j] = f2bf(accr[j] * invc);
        ((unsigned short*)&pi)[j] = f2bf(acci[j] * invc);
    }
    *(bf16x8*)&dr[((size_t)kb * PIX + gpix) * 8] = pr;
    *(bf16x8*)&di[((size_t)kb * PIX + gpix) * 8] = pi;
}

// ======================= 32-value block reduce -> atomics (8ch x {sr,qr,si,qi}) =======================
__device__ __forceinline__ void reduce32_commit(
    float* st, int kb, float* __restrict__ ssum)
{
#pragma unroll
    for (int v = 0; v < 32; ++v)
#pragma unroll
        for (int msk = 1; msk < 64; msk <<= 1)
            st[v] += __shfl_xor(st[v], msk, 64);
    __shared__ float red[4][32];
    const int wv = threadIdx.x >> 6;
    if ((threadIdx.x & 63) == 0)
#pragma unroll
        for (int v = 0; v < 32; ++v) red[wv][v] = st[v];
    __syncthreads();
    if (threadIdx.x < 32) {
        float s = red[0][threadIdx.x] + red[1][threadIdx.x] +
                  red[2][threadIdx.x] + red[3][threadIdx.x];
        int ch = kb * 8 + (threadIdx.x >> 2);
        int stat = threadIdx.x & 3;
        int base = (stat < 2) ? ch : 96 + ch;
        atomicAdd(&ssum[base * 2 + (stat & 1)], s);
    }
}

// ======================= s1 = x + proj -> PACKED bf16 directly + BN1 stats =======================
// grid: 12 kgroups x 36 pixblocks; thread: 4 pixels (stride 256) x 8 channels
__global__ __launch_bounds__(256) void combine_pack_kernel(
    const float* __restrict__ xr, const float* __restrict__ xi,
    const float* __restrict__ pr, const float* __restrict__ pi,
    unsigned short* __restrict__ dr, unsigned short* __restrict__ di,
    float* __restrict__ ssum)
{
    const int kb = blockIdx.x / 36;
    const int pb = blockIdx.x % 36;
    const int p0 = pb * 1024;
    float st[32];
#pragma unroll
    for (int v = 0; v < 32; ++v) st[v] = 0.f;

#pragma unroll
    for (int it = 0; it < 4; ++it) {
        int p = p0 + it * 256 + threadIdx.x;
        bf16x8 vr, vi;
#pragma unroll
        for (int ch = 0; ch < 8; ++ch) {
            int c = kb * 8 + ch;
            float a = xr[(size_t)c * PIX + p] + pr[(size_t)c * PIX + p];
            float b = xi[(size_t)c * PIX + p] + pi[(size_t)c * PIX + p];
            ((unsigned short*)&vr)[ch] = f2bf(a);
            ((unsigned short*)&vi)[ch] = f2bf(b);
            st[ch * 4 + 0] += a; st[ch * 4 + 1] += a * a;
            st[ch * 4 + 2] += b; st[ch * 4 + 3] += b * b;
        }
        *(bf16x8*)&dr[((size_t)kb * PIX + p) * 8] = vr;
        *(bf16x8*)&di[((size_t)kb * PIX + p) * 8] = vi;
    }
    reduce32_commit(st, kb, ssum);
}

// ======================= build BN1-folded mlp1 weights + bias (inline stats from ssum1) =======================
__global__ __launch_bounds__(256) void scale_w_kernel(
    const float* __restrict__ w1r, const float* __restrict__ w1i,
    const float* __restrict__ gr, const float* __restrict__ br,
    const float* __restrict__ gi, const float* __restrict__ bi,
    const float* __restrict__ ssum1,
    unsigned short* __restrict__ W0, unsigned short* __restrict__ W1,
    unsigned short* __restrict__ W2, unsigned short* __restrict__ W3,
    float* __restrict__ biasR, float* __restrict__ biasI)
{
    const float invn = 1.0f / (float)PIX;
    int blk = blockIdx.x;
    if (blk < 576) {
        int e = blk * 256 + threadIdx.x;        // 0..147455
        int mat = e / 36864;
        int idx = e % 36864;
        int k = idx % 96;
        float mr = ssum1[k * 2] * invn;
        float a_r = gr[k] * rsqrtf(ssum1[k * 2 + 1] * invn - mr * mr + 1e-5f);
        float mi = ssum1[(96 + k) * 2] * invn;
        float a_i = gi[k] * rsqrtf(ssum1[(96 + k) * 2 + 1] * invn - mi * mi + 1e-5f);
        float wr = w1r[idx], wi = w1i[idx];
        float v = (mat == 0) ? wr * a_r : (mat == 1) ? -wi * a_i
                : (mat == 2) ? wr * a_i : wi * a_r;
        unsigned short* dst = (mat == 0) ? W0 : (mat == 1) ? W1 : (mat == 2) ? W2 : W3;
        dst[idx] = f2bf(v);
    } else {
        int o = (blk - 576) * 256 + threadIdx.x;   // 0..767
        if (o >= 768) return;
        int isI = o >= 384;
        int oo = o % 384;
        float acc = 0.f;
        for (int k = 0; k < 96; ++k) {
            float mr = ssum1[k * 2] * invn;
            float a_r = gr[k] * rsqrtf(ssum1[k * 2 + 1] * invn - mr * mr + 1e-5f);
            float c_r = br[k] - a_r * mr;
            float mi = ssum1[(96 + k) * 2] * invn;
            float a_i = gi[k] * rsqrtf(ssum1[(96 + k) * 2 + 1] * invn - mi * mi + 1e-5f);
            float c_i = bi[k] - a_i * mi;
            float wr = w1r[oo * 96 + k], wi = w1i[oo * 96 + k];
            acc += isI ? (wr * c_i + wi * c_r) : (wr * c_r - wi * c_i);
        }
        (isI ? biasI : biasR)[oo] = acc;
    }
}

// ======================= mlp1 with folded BN1 + bias + cgelu -> packed bf16 hidden =======================
__global__ __launch_bounds__(256, 2) void mlp1bn_kernel(
    const unsigned short* __restrict__ W0, const unsigned short* __restrict__ W1,
    const unsigned short* __restrict__ W2, const unsigned short* __restrict__ W3,
    const float* __restrict__ biasR, const float* __restrict__ biasI,
    const unsigned short* __restrict__ Xr, const unsigned short* __restrict__ Xi,
    unsigned short* __restrict__ Pr, unsigned short* __restrict__ Pi, int N)
{
    const int lane = threadIdx.x & 63;
    const int wave = threadIdx.x >> 6;
    const int g = lane >> 4;
    const int r = lane & 15;
    const int m0 = (blockIdx.x % 12) * 32;
    const int n0 = (blockIdx.x / 12) * 256 + wave * 64;
    const int K = 96;

    floatx4 accR[2][4], accI[2][4];
#pragma unroll
    for (int t = 0; t < 2; ++t)
#pragma unroll
        for (int j = 0; j < 4; ++j) {
            accR[t][j] = (floatx4){0.f, 0.f, 0.f, 0.f};
            accI[t][j] = (floatx4){0.f, 0.f, 0.f, 0.f};
        }

    for (int kc = 0; kc < K; kc += 32) {
        bf16x8 a0[2], a1[2], a2[2], a3[2];
#pragma unroll
        for (int t = 0; t < 2; ++t) {
            size_t wb = (size_t)(m0 + t * 16 + r) * K + kc + g * 8;
            a0[t] = *(const bf16x8*)&W0[wb];
            a1[t] = *(const bf16x8*)&W1[wb];
            a2[t] = *(const bf16x8*)&W2[wb];
            a3[t] = *(const bf16x8*)&W3[wb];
        }
        bf16x8 bxr[4], bxi[4];
        const size_t krow = (size_t)((kc >> 3) + g);
#pragma unroll
        for (int j = 0; j < 4; ++j) {
            size_t off = (krow * N + n0 + j * 16 + r) * 8;
            bxr[j] = *(const bf16x8*)&Xr[off];
            bxi[j] = *(const bf16x8*)&Xi[off];
        }
#pragma unroll
        for (int t = 0; t < 2; ++t)
#pragma unroll
            for (int j = 0; j < 4; ++j) {
                accR[t][j] = __builtin_amdgcn_mfma_f32_16x16x32_bf16(a0[t], bxr[j], accR[t][j], 0, 0, 0);
                accR[t][j] = __builtin_amdgcn_mfma_f32_16x16x32_bf16(a1[t], bxi[j], accR[t][j], 0, 0, 0);
                accI[t][j] = __builtin_amdgcn_mfma_f32_16x16x32_bf16(a2[t], bxi[j], accI[t][j], 0, 0, 0);
                accI[t][j] = __builtin_amdgcn_mfma_f32_16x16x32_bf16(a3[t], bxr[j], accI[t][j], 0, 0, 0);
            }
    }

    // bias + cgelu + packed store
#pragma unroll
    for (int t = 0; t < 2; ++t) {
        float bR[4], bI[4];
#pragma unroll
        for (int reg = 0; reg < 4; ++reg) {
            int row = m0 + t * 16 + g * 4 + reg;
            bR[reg] = biasR[row];
            bI[reg] = biasI[row];
        }
#pragma unroll
        for (int j = 0; j < 4; ++j) {
            int col = n0 + j * 16 + r;
            size_t rowblk = (size_t)((m0 + t * 16 + g * 4) >> 3);
            int sub = (g & 1) * 4;
            bf16x4 pr, pi;
#pragma unroll
            for (int reg = 0; reg < 4; ++reg) {
                float a = accR[t][j][reg] + bR[reg];
                float b = accI[t][j][reg] + bI[reg];
                float mag = sqrtf(a * a + b * b);
                float f = (0.5f + 0.5f * erff(mag * 0.70710678118654752f)) * mag * RCP(mag + 1e-8f);
                ((unsigned short*)&pr)[reg] = f2bf(a * f);
                ((unsigned short*)&pi)[reg] = f2bf(b * f);
            }
            *(bf16x4*)&Pr[(rowblk * N + col) * 8 + sub] = pr;
            *(bf16x4*)&Pi[(rowblk * N + col) * 8 + sub] = pi;
        }
    }
}

// ======================= s2 = m + bn1(s1) -> bf16 planar + BN2 stats (inline stats1) =======================
__global__ __launch_bounds__(256) void addbn_kernel(
    const unsigned short* __restrict__ dr, const unsigned short* __restrict__ di,  // packed s1
    const float* __restrict__ ssum1,
    const float* __restrict__ gr, const float* __restrict__ br,
    const float* __restrict__ gi, const float* __restrict__ bi,
    const float* __restrict__ mr_, const float* __restrict__ mi_,
    unsigned short* __restrict__ s2r, unsigned short* __restrict__ s2i,
    float* __restrict__ ssum2)
{
    const int kb = blockIdx.x / 36;
    const int pb = blockIdx.x % 36;
    const int p0 = pb * 1024;
    const float invn = 1.0f / (float)PIX;

    float ar[8], cr[8], ai[8], ci[8];
#pragma unroll
    for (int ch = 0; ch < 8; ++ch) {
        int c = kb * 8 + ch;
        float mr = ssum1[c * 2] * invn;
        ar[ch] = gr[c] * rsqrtf(ssum1[c * 2 + 1] * invn - mr * mr + 1e-5f);
        cr[ch] = br[c] - ar[ch] * mr;
        float mi = ssum1[(96 + c) * 2] * invn;
        ai[ch] = gi[c] * rsqrtf(ssum1[(96 + c) * 2 + 1] * invn - mi * mi + 1e-5f);
        ci[ch] = bi[c] - ai[ch] * mi;
    }

    float st[32];
#pragma unroll
    for (int v = 0; v < 32; ++v) st[v] = 0.f;

#pragma unroll
    for (int it = 0; it < 4; ++it) {
        int p = p0 + it * 256 + threadIdx.x;
        bf16x8 s1r = *(const bf16x8*)&dr[((size_t)kb * PIX + p) * 8];
        bf16x8 s1i = *(const bf16x8*)&di[((size_t)kb * PIX + p) * 8];
#pragma unroll
        for (int ch = 0; ch < 8; ++ch) {
            int c = kb * 8 + ch;
            float vr = mr_[(size_t)c * PIX + p] + ar[ch] * bf2f((unsigned short)s1r[ch]) + cr[ch];
            float vi = mi_[(size_t)c * PIX + p] + ai[ch] * bf2f((unsigned short)s1i[ch]) + ci[ch];
            s2r[(size_t)c * PIX + p] = f2bf(vr);
            s2i[(size_t)c * PIX + p] = f2bf(vi);
            st[ch * 4 + 0] += vr; st[ch * 4 + 1] += vr * vr;
            st[ch * 4 + 2] += vi; st[ch * 4 + 3] += vi * vi;
        }
    }
    reduce32_commit(st, kb, ssum2);
}

// ======================= final BN2 apply (inline stats2, bf16 input) =======================
__global__ __launch_bounds__(256) void bn_apply_kernel(
    const unsigned short* __restrict__ s2r, const unsigned short* __restrict__ s2i,
    const float* __restrict__ gr, const float* __restrict__ br,
    const float* __restrict__ gi, const float* __restrict__ bi,
    const float* __restrict__ ssum2,
    float* __restrict__ outr, float* __restrict__ outi)
{
    int e = blockIdx.x * 256 + threadIdx.x;
    if (e >= 96 * PIX) return;
    int ch = e / PIX;
    const float invn = 1.0f / (float)PIX;
    float mr = ssum2[ch * 2] * invn;
    float isr = rsqrtf(ssum2[ch * 2 + 1] * invn - mr * mr + 1e-5f);
    float mi = ssum2[(96 + ch) * 2] * invn;
    float isi = rsqrtf(ssum2[(96 + ch) * 2 + 1] * invn - mi * mi + 1e-5f);
    outr[e] = gr[ch] * (bf2f(s2r[e]) - mr) * isr + br[ch];
    outi[e] = gi[ch] * (bf2f(s2i[e]) - mi) * isi + bi[ch];
}

// ======================= launch =======================
extern "C" void kernel_launch(void* const* d_in, const int* in_sizes, int n_in,
                              void* d_out, int out_size, void* d_ws, size_t ws_size,
                              hipStream_t stream)
{
    const float* x_r     = (const float*)d_in[0];
    const float* x_i     = (const float*)d_in[1];
    const float* qkv_wr  = (const float*)d_in[2];
    const float* qkv_wi  = (const float*)d_in[3];
    const float* proj_wr = (const float*)d_in[4];
    const float* proj_wi = (const float*)d_in[5];
    const float* rel     = (const float*)d_in[6];
    const float* mlp1_wr = (const float*)d_in[7];
    const float* mlp1_wi = (const float*)d_in[8];
    const float* mlp2_wr = (const float*)d_in[9];
    const float* mlp2_wi = (const float*)d_in[10];
    const float* n1_gr   = (const float*)d_in[11];
    const float* n1_br   = (const float*)d_in[12];
    const float* n1_gi   = (const float*)d_in[13];
    const float* n1_bi   = (const float*)d_in[14];
    const float* n2_gr   = (const float*)d_in[15];
    const float* n2_br   = (const float*)d_in[16];
    const float* n2_gi   = (const float*)d_in[17];
    const float* n2_bi   = (const float*)d_in[18];

    const size_t P = PIX;
    char* base = (char*)d_ws;

    unsigned short* Dr = (unsigned short*)base;           // packed operand / packed s1
    unsigned short* Di = Dr + 96 * P;
    char* R = (char*)(Di + 96 * P);                       // overlay region
    unsigned short* qkvb = (unsigned short*)R;            // 576*P ushorts
    unsigned short* wout = qkvb + 576 * P;                // NWIN*32*96*2 ushorts
    float* A_r = (float*)R;                               // proj out / m
    float* A_i = A_r + 96 * P;
    unsigned short* hid_r = (unsigned short*)(A_i + 96 * P);   // packed hidden re
    unsigned short* hid_i = hid_r + 384 * P;                    // packed hidden im
    unsigned short* Wb = wout + (size_t)NWIN * 32 * 96 * 2;

    unsigned short* wq = Wb;                    // 3 x 27648
    unsigned short* wp = Wb + 82944;            // 3 x 9216
    unsigned short* w2 = Wb + 110592;           // 3 x 36864
    unsigned short* W1s = Wb + 221184;          // 4 x 36864 (BN-folded mlp1)
    float* biasR = (float*)(Wb + 368640);
    float* biasI = biasR + 384;
    float* ssum1 = biasI + 384;
    float* ssum2 = ssum1 + 384;
    unsigned short* s2r = (unsigned short*)(ssum2 + 384);
    unsigned short* s2i = s2r + 96 * P;

    float* out_r = (float*)d_out;
    float* out_i = out_r + 96 * P;

    dim3 blk(256);

    // 0. weights -> bf16 + zero ssum (one dispatch)
    wconv_all_kernel<<<dim3(289), blk, 0, stream>>>(
        qkv_wr, qkv_wi, proj_wr, proj_wi, mlp2_wr, mlp2_wi, wq, wp, w2, ssum1);
    // 1. pack x
    pack_kernel<<<dim3(144, 12), blk, 0, stream>>>(x_r, x_i, Dr, Di, PIX);
    // 2. QKV gemm -> qkvb
    cgemm_mfma_kernel<96, 9, 2><<<dim3(9 * 144), blk, 0, stream>>>(
        wq, wq + 27648, wq + 55296, Dr, Di, nullptr, nullptr, qkvb, PIX);
    // 3. attention -> wout
    attn_mfma_kernel<<<dim3((NTASK + 3) / 4), blk, 0, stream>>>(qkvb, rel, wout);
    // 4. fold + /counts + pack for proj
    fold_pack_kernel<<<dim3(1728), blk, 0, stream>>>(wout, Dr, Di);
    // 5. proj gemm -> fp32 planar A
    cgemm_mfma_kernel<96, 3, 0><<<dim3(3 * 144), blk, 0, stream>>>(
        wp, wp + 9216, wp + 18432, Dr, Di, A_r, A_i, nullptr, PIX);
    // 6. s1 = x + proj -> packed bf16 directly + BN1 stats
    combine_pack_kernel<<<dim3(432), blk, 0, stream>>>(x_r, x_i, A_r, A_i, Dr, Di, ssum1);
    // 7. build BN1-folded mlp1 weights + bias (inline stats1)
    scale_w_kernel<<<dim3(579), blk, 0, stream>>>(
        mlp1_wr, mlp1_wi, n1_gr, n1_br, n1_gi, n1_bi, ssum1,
        W1s, W1s + 36864, W1s + 73728, W1s + 110592, biasR, biasI);
    // 8. mlp1 (BN folded) + bias + cgelu -> packed hidden
    mlp1bn_kernel<<<dim3(12 * 144), blk, 0, stream>>>(
        W1s, W1s + 36864, W1s + 73728, W1s + 110592, biasR, biasI,
        Dr, Di, hid_r, hid_i, PIX);
    // 9. mlp2 gemm -> m (fp32 planar A)
    cgemm_mfma_kernel<384, 3, 0><<<dim3(3 * 144), blk, 0, stream>>>(
        w2, w2 + 36864, w2 + 73728, hid_r, hid_i, A_r, A_i, nullptr, PIX);
    // 10. s2 = m + bn1(s1) -> bf16 planar + BN2 stats (inline stats1)
    addbn_kernel<<<dim3(432), blk, 0, stream>>>(Dr, Di, ssum1,
        n1_gr, n1_br, n1_gi, n1_bi, A_r, A_i, s2r, s2i, ssum2);
    // 11. BN2 apply (inline stats2) -> out
    bn_apply_kernel<<<dim3(13824), blk, 0, stream>>>(s2r, s2i,
        n2_gr, n2_br, n2_gi, n2_bi, ssum2, out_r, out_i);
}

// Round 10
// 343.956 us; speedup vs baseline: 1.2215x; 1.0072x over previous
//
#include <hip/hip_runtime.h>
#include <math.h>

#define PIX 36864          // 192*192
#define IMW 192
#define NWIN 4465          // 47*95
#define NWIN_W 95
#define NTASK (NWIN * 6)

typedef short bf16x8 __attribute__((ext_vector_type(8)));
typedef short bf16x4 __attribute__((ext_vector_type(4)));
typedef float floatx4 __attribute__((ext_vector_type(4)));

#if defined(__has_builtin)
#  if __has_builtin(__builtin_amdgcn_rcpf)
#    define RCP(x) __builtin_amdgcn_rcpf(x)
#  endif
#endif
#ifndef RCP
#  define RCP(x) (1.0f / (x))
#endif

__device__ __forceinline__ unsigned short f2bf(float f) {
    union { float f; unsigned u; } v; v.f = f;
    unsigned r = v.u + 0x7fff + ((v.u >> 16) & 1);   // RNE
    return (unsigned short)(r >> 16);
}
__device__ __forceinline__ float bf2f(unsigned short b) {
    union { unsigned u; float f; } v; v.u = ((unsigned)b) << 16;
    return v.f;
}

// ======================= weights->bf16 + ssum zero + pack x : ONE dispatch =======================
__device__ __forceinline__ void emit3(
    const float* __restrict__ wr, const float* __restrict__ wi,
    unsigned short* __restrict__ outr, unsigned short* __restrict__ outi,
    unsigned short* __restrict__ outni, int e)
{
    outr[e] = f2bf(wr[e]);
    unsigned short b = f2bf(wi[e]);
    outi[e]  = b;
    outni[e] = b ^ 0x8000;
}

__global__ __launch_bounds__(256) void prep_kernel(
    const float* __restrict__ qwr, const float* __restrict__ qwi,
    const float* __restrict__ pwr, const float* __restrict__ pwi,
    const float* __restrict__ w2r, const float* __restrict__ w2i,
    const float* __restrict__ xr,  const float* __restrict__ xi,
    unsigned short* __restrict__ wq, unsigned short* __restrict__ wp,
    unsigned short* __restrict__ w2, float* __restrict__ ssum,
    unsigned short* __restrict__ dr, unsigned short* __restrict__ di)
{
    int blk = blockIdx.x;
    if (blk < 108)      { emit3(qwr, qwi, wq, wq + 27648, wq + 55296, blk * 256 + threadIdx.x); return; }
    if (blk < 144)      { emit3(pwr, pwi, wp, wp + 9216,  wp + 18432, (blk - 108) * 256 + threadIdx.x); return; }
    if (blk < 288)      { emit3(w2r, w2i, w2, w2 + 36864, w2 + 73728, (blk - 144) * 256 + threadIdx.x); return; }
    if (blk == 288)     { for (int j = threadIdx.x; j < 768; j += 256) ssum[j] = 0.f; return; }
    // pack x: blocks 289..2016
    int e  = blk - 289;                 // 0..1727
    int kb = e / 144;
    int n  = (e % 144) * 256 + threadIdx.x;
    bf16x8 vr, vi;
#pragma unroll
    for (int j = 0; j < 8; ++j) {
        ((unsigned short*)&vr)[j] = f2bf(xr[(size_t)(kb * 8 + j) * PIX + n]);
        ((unsigned short*)&vi)[j] = f2bf(xi[(size_t)(kb * 8 + j) * PIX + n]);
    }
    *(bf16x8*)&dr[((size_t)kb * PIX + n) * 8] = vr;
    *(bf16x8*)&di[((size_t)kb * PIX + n) * 8] = vi;
}

// ======================= complex GEMM via MFMA =======================
// STORE: 2 = qkvb pixel-major slot | 3 = bf16 planar (Pr=re, Pi=im)
template<int K, int MT, int STORE>
__global__ __launch_bounds__(256, 2) void cgemm_mfma_kernel(
    const unsigned short* __restrict__ Wr, const unsigned short* __restrict__ Wi,
    const unsigned short* __restrict__ Wni,
    const unsigned short* __restrict__ Xr, const unsigned short* __restrict__ Xi,
    unsigned short* __restrict__ Pr, unsigned short* __restrict__ Pi, int N)
{
    const int lane = threadIdx.x & 63;
    const int wave = threadIdx.x >> 6;
    const int g = lane >> 4;
    const int r = lane & 15;
    const int m0 = (blockIdx.x % MT) * 32;
    const int n0 = (blockIdx.x / MT) * 256 + wave * 64;

    floatx4 accR[2][4], accI[2][4];
#pragma unroll
    for (int t = 0; t < 2; ++t)
#pragma unroll
        for (int j = 0; j < 4; ++j) {
            accR[t][j] = (floatx4){0.f, 0.f, 0.f, 0.f};
            accI[t][j] = (floatx4){0.f, 0.f, 0.f, 0.f};
        }

    for (int kc = 0; kc < K; kc += 32) {
        bf16x8 awr[2], awi[2], awni[2];
#pragma unroll
        for (int t = 0; t < 2; ++t) {
            size_t wb = (size_t)(m0 + t * 16 + r) * K + kc + g * 8;
            awr[t]  = *(const bf16x8*)&Wr[wb];
            awi[t]  = *(const bf16x8*)&Wi[wb];
            awni[t] = *(const bf16x8*)&Wni[wb];
        }
        bf16x8 bxr[4], bxi[4];
        const size_t krow = (size_t)((kc >> 3) + g);
#pragma unroll
        for (int j = 0; j < 4; ++j) {
            size_t off = (krow * N + n0 + j * 16 + r) * 8;
            bxr[j] = *(const bf16x8*)&Xr[off];
            bxi[j] = *(const bf16x8*)&Xi[off];
        }
#pragma unroll
        for (int t = 0; t < 2; ++t)
#pragma unroll
            for (int j = 0; j < 4; ++j) {
                accR[t][j] = __builtin_amdgcn_mfma_f32_16x16x32_bf16(awr[t],  bxr[j], accR[t][j], 0, 0, 0);
                accR[t][j] = __builtin_amdgcn_mfma_f32_16x16x32_bf16(awni[t], bxi[j], accR[t][j], 0, 0, 0);
                accI[t][j] = __builtin_amdgcn_mfma_f32_16x16x32_bf16(awr[t],  bxi[j], accI[t][j], 0, 0, 0);
                accI[t][j] = __builtin_amdgcn_mfma_f32_16x16x32_bf16(awi[t],  bxr[j], accI[t][j], 0, 0, 0);
            }
    }

    if (STORE == 3) {
#pragma unroll
        for (int t = 0; t < 2; ++t)
#pragma unroll
            for (int j = 0; j < 4; ++j) {
                int col = n0 + j * 16 + r;
#pragma unroll
                for (int reg = 0; reg < 4; ++reg) {
                    int row = m0 + t * 16 + g * 4 + reg;
                    Pr[(size_t)row * N + col] = f2bf(accR[t][j][reg]);
                    Pi[(size_t)row * N + col] = f2bf(accI[t][j][reg]);
                }
            }
    } else {
#pragma unroll
        for (int t = 0; t < 2; ++t) {
            int ch0 = m0 + t * 16;
            int which = ch0 / 96;
            int hh = (ch0 % 96) / 16;
#pragma unroll
            for (int j = 0; j < 4; ++j) {
                int col = n0 + j * 16 + r;
                bf16x4 pr, pi;
#pragma unroll
                for (int reg = 0; reg < 4; ++reg) {
                    ((unsigned short*)&pr)[reg] = f2bf(accR[t][j][reg]);
                    ((unsigned short*)&pi)[reg] = f2bf(accI[t][j][reg]);
                }
                size_t sb = (((size_t)col * 3 + which) * 6 + hh) * 32;
                *(bf16x4*)&Pr[sb + g * 4]      = pr;
                *(bf16x4*)&Pr[sb + 16 + g * 4] = pi;
            }
        }
    }
}

// ======================= MFMA attention (epilogue -> pixel-major slot layout) =======================
__global__ __launch_bounds__(256) void attn_mfma_kernel(
    const unsigned short* __restrict__ qkvb,
    const float* __restrict__ rel,
    unsigned short* __restrict__ wout)
{
    __shared__ unsigned aLDS[4][32 * 36];
    __shared__ unsigned vLDS[4][32 * 17];

    const int wv   = threadIdx.x >> 6;
    const int lane = threadIdx.x & 63;
    const int lr   = lane & 15;
    const int g    = lane >> 4;

    int t = blockIdx.x * 4 + wv;
    if (t >= NTASK) t = NTASK - 1;
    const int w = t / 6, h = t % 6;
    const int nh = w / NWIN_W, nw = w % NWIN_W;
    const int r0 = nh * 4, c0 = nw * 2;
    const int slot = ((nh & 1) << 1) | (nw & 1);

    unsigned* AL = aLDS[wv];
    unsigned* VL = vLDS[wv];

    auto slotq = [&](int p, int which) -> size_t {
        int gpix = (r0 + (p >> 2)) * IMW + c0 + (p & 3);
        return ((size_t)gpix * 18 + which * 6 + h) * 32;
    };

    {
        int m = lane & 31;
        int half = lane >> 5;
        size_t sv = slotq(m, 2);
        const bf16x8 vr = *(const bf16x8*)&qkvb[sv + half * 8];
        const bf16x8 vi = *(const bf16x8*)&qkvb[sv + 16 + half * 8];
#pragma unroll
        for (int j = 0; j < 8; ++j) {
            unsigned pk = (unsigned)(unsigned short)vr[j] |
                          ((unsigned)(unsigned short)vi[j] << 16);
            VL[m * 17 + half * 8 + j] = pk;
        }
    }

    const int hoff = (g >> 1) * 16;
    const int loff = (g & 1) * 8;
    const unsigned sm = (g >= 2) ? 0x80008000u : 0u;
    bf16x8 Are[2], Aim[2], Bre[2], Bim[2];
#pragma unroll
    for (int tt = 0; tt < 2; ++tt) {
        size_t sq = slotq(tt * 16 + lr, 0);
        size_t sk = slotq(tt * 16 + lr, 1);
        Are[tt] = *(const bf16x8*)&qkvb[sq + hoff + loff];
        Aim[tt] = *(const bf16x8*)&qkvb[sq + (16 - hoff) + loff];
        Bre[tt] = *(const bf16x8*)&qkvb[sk + hoff + loff];
        bf16x8 tmp = Bre[tt];
        unsigned* u = (unsigned*)&tmp;
        u[0] ^= sm; u[1] ^= sm; u[2] ^= sm; u[3] ^= sm;
        Bim[tt] = tmp;
    }

    const floatx4 z4 = (floatx4){0.f, 0.f, 0.f, 0.f};
    floatx4 Sre[2][2], Sim[2][2];
#pragma unroll
    for (int tn = 0; tn < 2; ++tn)
#pragma unroll
        for (int tm = 0; tm < 2; ++tm) {
            Sre[tn][tm] = __builtin_amdgcn_mfma_f32_16x16x32_bf16(Are[tn], Bre[tm], z4, 0, 0, 0);
            Sim[tn][tm] = __builtin_amdgcn_mfma_f32_16x16x32_bf16(Aim[tn], Bim[tm], z4, 0, 0, 0);
        }

    const float* relh = rel + h * 105;
#pragma unroll
    for (int tn = 0; tn < 2; ++tn)
#pragma unroll
        for (int tm = 0; tm < 2; ++tm) {
            int m = tm * 16 + lr;
            int ym = m >> 2, xm = m & 3;
            int yn = tn * 4 + g;
            int bidx = (yn - ym + 7) * 7 + (3 - xm);
#pragma unroll
            for (int reg = 0; reg < 4; ++reg) {
                float re = Sre[tn][tm][reg] * 0.25f + relh[bidx + reg];
                float im = Sim[tn][tm][reg] * 0.25f;
                int n = tn * 16 + g * 4 + reg;
                AL[n * 36 + m] = (unsigned)f2bf(re) | ((unsigned)f2bf(im) << 16);
            }
        }
    __syncthreads();

    {
        const int row = lane & 31;
        const int half = lane >> 5;
        unsigned* rp = &AL[row * 36 + half * 16];
        unsigned pk[16];
        *(uint4*)&pk[0]  = *(const uint4*)&rp[0];
        *(uint4*)&pk[4]  = *(const uint4*)&rp[4];
        *(uint4*)&pk[8]  = *(const uint4*)&rp[8];
        *(uint4*)&pk[12] = *(const uint4*)&rp[12];
        float re[16], im[16], mg[16];
#pragma unroll
        for (int j = 0; j < 16; ++j) {
            union { unsigned u; float f; } a, b;
            a.u = pk[j] << 16;
            b.u = pk[j] & 0xffff0000u;
            re[j] = a.f; im[j] = b.f;
            mg[j] = sqrtf(a.f * a.f + b.f * b.f);
        }
        float mx = mg[0];
#pragma unroll
        for (int j = 1; j < 16; ++j) mx = fmaxf(mx, mg[j]);
        mx = fmaxf(mx, __shfl_xor(mx, 32, 64));
        float es[16], ss = 0.f;
#pragma unroll
        for (int j = 0; j < 16; ++j) { es[j] = __expf(mg[j] - mx); ss += es[j]; }
        ss += __shfl_xor(ss, 32, 64);
        float inv = RCP(ss);
#pragma unroll
        for (int j = 0; j < 16; ++j) {
            float f = es[j] * inv * RCP(mg[j] + 1e-8f);
            pk[j] = (unsigned)f2bf(re[j] * f) | ((unsigned)f2bf(im[j] * f) << 16);
        }
        *(uint4*)&rp[0]  = *(uint4*)&pk[0];
        *(uint4*)&rp[4]  = *(uint4*)&pk[4];
        *(uint4*)&rp[8]  = *(uint4*)&pk[8];
        *(uint4*)&rp[12] = *(uint4*)&pk[12];
    }
    __syncthreads();

    floatx4 Pre[2] = {z4, z4}, Pim[2] = {z4, z4};
#pragma unroll
    for (int kc = 0; kc < 2; ++kc) {
        bf16x8 Bpr, Bpi;
        unsigned* bpr = (unsigned*)&Bpr;
        unsigned* bpi = (unsigned*)&Bpi;
#pragma unroll
        for (int p = 0; p < 4; ++p) {
            unsigned pv = VL[(kc * 16 + g * 4 + p) * 17 + lr];
            bpr[p] = pv ^ 0x80000000u;
            bpi[p] = (pv >> 16) | (pv << 16);
        }
#pragma unroll
        for (int tn = 0; tn < 2; ++tn) {
            bf16x8 Af = *(bf16x8*)&AL[(tn * 16 + lr) * 36 + kc * 16 + g * 4];
            Pre[tn] = __builtin_amdgcn_mfma_f32_16x16x32_bf16(Af, Bpr, Pre[tn], 0, 0, 0);
            Pim[tn] = __builtin_amdgcn_mfma_f32_16x16x32_bf16(Af, Bpi, Pim[tn], 0, 0, 0);
        }
    }

    // epilogue: wout[gpix][slot][ch][re,im]
#pragma unroll
    for (int tn = 0; tn < 2; ++tn)
#pragma unroll
        for (int reg = 0; reg < 4; ++reg) {
            int n = tn * 16 + g * 4 + reg;
            int gpix = (r0 + (n >> 2)) * IMW + c0 + (n & 3);
            int ch = h * 16 + lr;
            unsigned pk = (unsigned)f2bf(Pre[tn][reg]) |
                          ((unsigned)f2bf(Pim[tn][reg]) << 16);
            *(unsigned*)&wout[(((size_t)gpix * 4 + slot) * 96 + ch) * 2] = pk;
        }
}

// ======================= fold (pixel-major slots) + count-div + pack for proj =======================
__global__ __launch_bounds__(256) void fold_pack_kernel(
    const unsigned short* __restrict__ wout,
    unsigned short* __restrict__ dr, unsigned short* __restrict__ di)
{
    int e = blockIdx.x * 256 + threadIdx.x;   // PIX*12
    int gpix = e / 12;
    int kb   = e % 12;
    int r = gpix / IMW, c = gpix % IMW;
    int nh0 = (r >= 7) ? ((r - 4) >> 2) : 0;
    int nh1 = min(46, r >> 2);
    int nw0 = (c >= 3) ? ((c - 2) >> 1) : 0;
    int nw1 = min(94, c >> 1);

    float accr[8] = {0,0,0,0,0,0,0,0}, acci[8] = {0,0,0,0,0,0,0,0};
    int cnt = 0;
    for (int nh = nh0; nh <= nh1; ++nh)
        for (int nw = nw0; nw <= nw1; ++nw) {
            int slot = ((nh & 1) << 1) | (nw & 1);
            const unsigned short* src = &wout[(((size_t)gpix * 4 + slot) * 96 + kb * 8) * 2];
            bf16x8 a = *(const bf16x8*)&src[0];
            bf16x8 b = *(const bf16x8*)&src[8];
#pragma unroll
            for (int j = 0; j < 4; ++j) {
                accr[j]     += bf2f((unsigned short)a[j*2]);
                acci[j]     += bf2f((unsigned short)a[j*2+1]);
                accr[4 + j] += bf2f((unsigned short)b[j*2]);
                acci[4 + j] += bf2f((unsigned short)b[j*2+1]);
            }
            ++cnt;
        }
    float invc = 1.0f / ((float)cnt + 1e-8f);
    bf16x8 pr, pi;
#pragma unroll
    for (int j = 0; j < 8; ++j) {
        ((unsigned short*)&pr)[j] = f2bf(accr[j] * invc);
        ((unsigned short*)&pi)[j] = f2bf(acci[j] * invc);
    }
    *(bf16x8*)&dr[((size_t)kb * PIX + gpix) * 8] = pr;
    *(bf16x8*)&di[((size_t)kb * PIX + gpix) * 8] = pi;
}

// ======================= 32-value block reduce -> atomics =======================
__device__ __forceinline__ void reduce32_commit(
    float* st, int kb, float* __restrict__ ssum)
{
#pragma unroll
    for (int v = 0; v < 32; ++v)
#pragma unroll
        for (int msk = 1; msk < 64; msk <<= 1)
            st[v] += __shfl_xor(st[v], msk, 64);
    __shared__ float red[4][32];
    const int wv = threadIdx.x >> 6;
    if ((threadIdx.x & 63) == 0)
#pragma unroll
        for (int v = 0; v < 32; ++v) red[wv][v] = st[v];
    __syncthreads();
    if (threadIdx.x < 32) {
        float s = red[0][threadIdx.x] + red[1][threadIdx.x] +
                  red[2][threadIdx.x] + red[3][threadIdx.x];
        int ch = kb * 8 + (threadIdx.x >> 2);
        int stat = threadIdx.x & 3;
        int base = (stat < 2) ? ch : 96 + ch;
        atomicAdd(&ssum[base * 2 + (stat & 1)], s);
    }
}

// ======================= s1 = x + proj(bf16) -> packed bf16 + BN1 stats =======================
__global__ __launch_bounds__(256) void combine_pack_kernel(
    const float* __restrict__ xr, const float* __restrict__ xi,
    const unsigned short* __restrict__ pr, const unsigned short* __restrict__ pi,
    unsigned short* __restrict__ dr, unsigned short* __restrict__ di,
    float* __restrict__ ssum)
{
    const int kb = blockIdx.x / 36;
    const int pb = blockIdx.x % 36;
    const int p0 = pb * 1024;
    float st[32];
#pragma unroll
    for (int v = 0; v < 32; ++v) st[v] = 0.f;

#pragma unroll
    for (int it = 0; it < 4; ++it) {
        int p = p0 + it * 256 + threadIdx.x;
        bf16x8 vr, vi;
#pragma unroll
        for (int ch = 0; ch < 8; ++ch) {
            int c = kb * 8 + ch;
            float a = xr[(size_t)c * PIX + p] + bf2f(pr[(size_t)c * PIX + p]);
            float b = xi[(size_t)c * PIX + p] + bf2f(pi[(size_t)c * PIX + p]);
            ((unsigned short*)&vr)[ch] = f2bf(a);
            ((unsigned short*)&vi)[ch] = f2bf(b);
            st[ch * 4 + 0] += a; st[ch * 4 + 1] += a * a;
            st[ch * 4 + 2] += b; st[ch * 4 + 3] += b * b;
        }
        *(bf16x8*)&dr[((size_t)kb * PIX + p) * 8] = vr;
        *(bf16x8*)&di[((size_t)kb * PIX + p) * 8] = vi;
    }
    reduce32_commit(st, kb, ssum);
}

// ======================= build BN1-folded mlp1 weights + bias =======================
__global__ __launch_bounds__(256) void scale_w_kernel(
    const float* __restrict__ w1r, const float* __restrict__ w1i,
    const float* __restrict__ gr, const float* __restrict__ br,
    const float* __restrict__ gi, const float* __restrict__ bi,
    const float* __restrict__ ssum1,
    unsigned short* __restrict__ W0, unsigned short* __restrict__ W1,
    unsigned short* __restrict__ W2, unsigned short* __restrict__ W3,
    float* __restrict__ biasR, float* __restrict__ biasI)
{
    const float invn = 1.0f / (float)PIX;
    int blk = blockIdx.x;
    if (blk < 576) {
        int e = blk * 256 + threadIdx.x;
        int mat = e / 36864;
        int idx = e % 36864;
        int k = idx % 96;
        float mr = ssum1[k * 2] * invn;
        float a_r = gr[k] * rsqrtf(ssum1[k * 2 + 1] * invn - mr * mr + 1e-5f);
        float mi = ssum1[(96 + k) * 2] * invn;
        float a_i = gi[k] * rsqrtf(ssum1[(96 + k) * 2 + 1] * invn - mi * mi + 1e-5f);
        float wr = w1r[idx], wi = w1i[idx];
        float v = (mat == 0) ? wr * a_r : (mat == 1) ? -wi * a_i
                : (mat == 2) ? wr * a_i : wi * a_r;
        unsigned short* dst = (mat == 0) ? W0 : (mat == 1) ? W1 : (mat == 2) ? W2 : W3;
        dst[idx] = f2bf(v);
    } else {
        int o = (blk - 576) * 256 + threadIdx.x;
        if (o >= 768) return;
        int isI = o >= 384;
        int oo = o % 384;
        float acc = 0.f;
        for (int k = 0; k < 96; ++k) {
            float mr = ssum1[k * 2] * invn;
            float a_r = gr[k] * rsqrtf(ssum1[k * 2 + 1] * invn - mr * mr + 1e-5f);
            float c_r = br[k] - a_r * mr;
            float mi = ssum1[(96 + k) * 2] * invn;
            float a_i = gi[k] * rsqrtf(ssum1[(96 + k) * 2 + 1] * invn - mi * mi + 1e-5f);
            float c_i = bi[k] - a_i * mi;
            float wr = w1r[oo * 96 + k], wi = w1i[oo * 96 + k];
            acc += isI ? (wr * c_i + wi * c_r) : (wr * c_r - wi * c_i);
        }
        (isI ? biasI : biasR)[oo] = acc;
    }
}

// ======================= mlp1 (BN folded) + bias + cgelu -> packed bf16 hidden =======================
__global__ __launch_bounds__(256, 2) void mlp1bn_kernel(
    const unsigned short* __restrict__ W0, const unsigned short* __restrict__ W1,
    const unsigned short* __restrict__ W2, const unsigned short* __restrict__ W3,
    const float* __restrict__ biasR, const float* __restrict__ biasI,
    const unsigned short* __restrict__ Xr, const unsigned short* __restrict__ Xi,
    unsigned short* __restrict__ Pr, unsigned short* __restrict__ Pi, int N)
{
    const int lane = threadIdx.x & 63;
    const int wave = threadIdx.x >> 6;
    const int g = lane >> 4;
    const int r = lane & 15;
    const int m0 = (blockIdx.x % 12) * 32;
    const int n0 = (blockIdx.x / 12) * 256 + wave * 64;
    const int K = 96;

    floatx4 accR[2][4], accI[2][4];
#pragma unroll
    for (int t = 0; t < 2; ++t)
#pragma unroll
        for (int j = 0; j < 4; ++j) {
            accR[t][j] = (floatx4){0.f, 0.f, 0.f, 0.f};
            accI[t][j] = (floatx4){0.f, 0.f, 0.f, 0.f};
        }

    for (int kc = 0; kc < K; kc += 32) {
        bf16x8 a0[2], a1[2], a2[2], a3[2];
#pragma unroll
        for (int t = 0; t < 2; ++t) {
            size_t wb = (size_t)(m0 + t * 16 + r) * K + kc + g * 8;
            a0[t] = *(const bf16x8*)&W0[wb];
            a1[t] = *(const bf16x8*)&W1[wb];
            a2[t] = *(const bf16x8*)&W2[wb];
            a3[t] = *(const bf16x8*)&W3[wb];
        }
        bf16x8 bxr[4], bxi[4];
        const size_t krow = (size_t)((kc >> 3) + g);
#pragma unroll
        for (int j = 0; j < 4; ++j) {
            size_t off = (krow * N + n0 + j * 16 + r) * 8;
            bxr[j] = *(const bf16x8*)&Xr[off];
            bxi[j] = *(const bf16x8*)&Xi[off];
        }
#pragma unroll
        for (int t = 0; t < 2; ++t)
#pragma unroll
            for (int j = 0; j < 4; ++j) {
                accR[t][j] = __builtin_amdgcn_mfma_f32_16x16x32_bf16(a0[t], bxr[j], accR[t][j], 0, 0, 0);
                accR[t][j] = __builtin_amdgcn_mfma_f32_16x16x32_bf16(a1[t], bxi[j], accR[t][j], 0, 0, 0);
                accI[t][j] = __builtin_amdgcn_mfma_f32_16x16x32_bf16(a2[t], bxi[j], accI[t][j], 0, 0, 0);
                accI[t][j] = __builtin_amdgcn_mfma_f32_16x16x32_bf16(a3[t], bxr[j], accI[t][j], 0, 0, 0);
            }
    }

#pragma unroll
    for (int t = 0; t < 2; ++t) {
        float bR[4], bI[4];
#pragma unroll
        for (int reg = 0; reg < 4; ++reg) {
            int row = m0 + t * 16 + g * 4 + reg;
            bR[reg] = biasR[row];
            bI[reg] = biasI[row];
        }
#pragma unroll
        for (int j = 0; j < 4; ++j) {
            int col = n0 + j * 16 + r;
            size_t rowblk = (size_t)((m0 + t * 16 + g * 4) >> 3);
            int sub = (g & 1) * 4;
            bf16x4 pr, pi;
#pragma unroll
            for (int reg = 0; reg < 4; ++reg) {
                float a = accR[t][j][reg] + bR[reg];
                float b = accI[t][j][reg] + bI[reg];
                float mag = sqrtf(a * a + b * b);
                float f = (0.5f + 0.5f * erff(mag * 0.70710678118654752f)) * mag * RCP(mag + 1e-8f);
                ((unsigned short*)&pr)[reg] = f2bf(a * f);
                ((unsigned short*)&pi)[reg] = f2bf(b * f);
            }
            *(bf16x4*)&Pr[(rowblk * N + col) * 8 + sub] = pr;
            *(bf16x4*)&Pi[(rowblk * N + col) * 8 + sub] = pi;
        }
    }
}

// ======================= s2 = m(bf16) + bn1(s1) -> bf16 planar + BN2 stats =======================
__global__ __launch_bounds__(256) void addbn_kernel(
    const unsigned short* __restrict__ dr, const unsigned short* __restrict__ di,  // packed s1
    const float* __restrict__ ssum1,
    const float* __restrict__ gr, const float* __restrict__ br,
    const float* __restrict__ gi, const float* __restrict__ bi,
    const unsigned short* __restrict__ mr_, const unsigned short* __restrict__ mi_,
    unsigned short* __restrict__ s2r, unsigned short* __restrict__ s2i,
    float* __restrict__ ssum2)
{
    const int kb = blockIdx.x / 36;
    const int pb = blockIdx.x % 36;
    const int p0 = pb * 1024;
    const float invn = 1.0f / (float)PIX;

    float ar[8], cr[8], ai[8], ci[8];
#pragma unroll
    for (int ch = 0; ch < 8; ++ch) {
        int c = kb * 8 + ch;
        float mr = ssum1[c * 2] * invn;
        ar[ch] = gr[c] * rsqrtf(ssum1[c * 2 + 1] * invn - mr * mr + 1e-5f);
        cr[ch] = br[c] - ar[ch] * mr;
        float mi = ssum1[(96 + c) * 2] * invn;
        ai[ch] = gi[c] * rsqrtf(ssum1[(96 + c) * 2 + 1] * invn - mi * mi + 1e-5f);
        ci[ch] = bi[c] - ai[ch] * mi;
    }

    float st[32];
#pragma unroll
    for (int v = 0; v < 32; ++v) st[v] = 0.f;

#pragma unroll
    for (int it = 0; it < 4; ++it) {
        int p = p0 + it * 256 + threadIdx.x;
        bf16x8 s1r = *(const bf16x8*)&dr[((size_t)kb * PIX + p) * 8];
        bf16x8 s1i = *(const bf16x8*)&di[((size_t)kb * PIX + p) * 8];
#pragma unroll
        for (int ch = 0; ch < 8; ++ch) {
            int c = kb * 8 + ch;
            float vr = bf2f(mr_[(size_t)c * PIX + p]) + ar[ch] * bf2f((unsigned short)s1r[ch]) + cr[ch];
            float vi = bf2f(mi_[(size_t)c * PIX + p]) + ai[ch] * bf2f((unsigned short)s1i[ch]) + ci[ch];
            s2r[(size_t)c * PIX + p] = f2bf(vr);
            s2i[(size_t)c * PIX + p] = f2bf(vi);
            st[ch * 4 + 0] += vr; st[ch * 4 + 1] += vr * vr;
            st[ch * 4 + 2] += vi; st[ch * 4 + 3] += vi * vi;
        }
    }
    reduce32_commit(st, kb, ssum2);
}

// ======================= final BN2 apply =======================
__global__ __launch_bounds__(256) void bn_apply_kernel(
    const unsigned short* __restrict__ s2r, const unsigned short* __restrict__ s2i,
    const float* __restrict__ gr, const float* __restrict__ br,
    const float* __restrict__ gi, const float* __restrict__ bi,
    const float* __restrict__ ssum2,
    float* __restrict__ outr, float* __restrict__ outi)
{
    int e = blockIdx.x * 256 + threadIdx.x;
    if (e >= 96 * PIX) return;
    int ch = e / PIX;
    const float invn = 1.0f / (float)PIX;
    float mr = ssum2[ch * 2] * invn;
    float isr = rsqrtf(ssum2[ch * 2 + 1] * invn - mr * mr + 1e-5f);
    float mi = ssum2[(96 + ch) * 2] * invn;
    float isi = rsqrtf(ssum2[(96 + ch) * 2 + 1] * invn - mi * mi + 1e-5f);
    outr[e] = gr[ch] * (bf2f(s2r[e]) - mr) * isr + br[ch];
    outi[e] = gi[ch] * (bf2f(s2i[e]) - mi) * isi + bi[ch];
}

// ======================= launch =======================
extern "C" void kernel_launch(void* const* d_in, const int* in_sizes, int n_in,
                              void* d_out, int out_size, void* d_ws, size_t ws_size,
                              hipStream_t stream)
{
    const float* x_r     = (const float*)d_in[0];
    const float* x_i     = (const float*)d_in[1];
    const float* qkv_wr  = (const float*)d_in[2];
    const float* qkv_wi  = (const float*)d_in[3];
    const float* proj_wr = (const float*)d_in[4];
    const float* proj_wi = (const float*)d_in[5];
    const float* rel     = (const float*)d_in[6];
    const float* mlp1_wr = (const float*)d_in[7];
    const float* mlp1_wi = (const float*)d_in[8];
    const float* mlp2_wr = (const float*)d_in[9];
    const float* mlp2_wi = (const float*)d_in[10];
    const float* n1_gr   = (const float*)d_in[11];
    const float* n1_br   = (const float*)d_in[12];
    const float* n1_gi   = (const float*)d_in[13];
    const float* n1_bi   = (const float*)d_in[14];
    const float* n2_gr   = (const float*)d_in[15];
    const float* n2_br   = (const float*)d_in[16];
    const float* n2_gi   = (const float*)d_in[17];
    const float* n2_bi   = (const float*)d_in[18];

    const size_t P = PIX;
    char* base = (char*)d_ws;

    unsigned short* Dr = (unsigned short*)base;           // packed operand / packed s1
    unsigned short* Di = Dr + 96 * P;
    char* R = (char*)(Di + 96 * P);                       // overlay region
    unsigned short* qkvb = (unsigned short*)R;            // 576*P ushorts
    unsigned short* wout = qkvb + 576 * P;                // PIX*4*96*2 ushorts (pixel-major slots)
    unsigned short* pm_r = (unsigned short*)R;            // proj / m bf16 planar (96*P each)
    unsigned short* pm_i = pm_r + 96 * P;
    unsigned short* hid_r = pm_i + 96 * P;                // packed hidden re (384*P)
    unsigned short* hid_i = hid_r + 384 * P;              // packed hidden im
    unsigned short* Wb = wout + (size_t)P * 4 * 96 * 2;

    unsigned short* wq = Wb;                    // 3 x 27648
    unsigned short* wp = Wb + 82944;            // 3 x 9216
    unsigned short* w2 = Wb + 110592;           // 3 x 36864
    unsigned short* W1s = Wb + 221184;          // 4 x 36864 (BN-folded mlp1)
    float* biasR = (float*)(Wb + 368640);
    float* biasI = biasR + 384;
    float* ssum1 = biasI + 384;
    float* ssum2 = ssum1 + 384;
    unsigned short* s2r = (unsigned short*)(ssum2 + 384);
    unsigned short* s2i = s2r + 96 * P;

    float* out_r = (float*)d_out;
    float* out_i = out_r + 96 * P;

    dim3 blk(256);

    // 0. weights -> bf16 + zero ssum + pack x (ONE dispatch)
    prep_kernel<<<dim3(2017), blk, 0, stream>>>(
        qkv_wr, qkv_wi, proj_wr, proj_wi, mlp2_wr, mlp2_wi, x_r, x_i,
        wq, wp, w2, ssum1, Dr, Di);
    // 1. QKV gemm -> qkvb
    cgemm_mfma_kernel<96, 9, 2><<<dim3(9 * 144), blk, 0, stream>>>(
        wq, wq + 27648, wq + 55296, Dr, Di, qkvb, nullptr, PIX);
    // 2. attention -> wout (pixel-major slots)
    attn_mfma_kernel<<<dim3((NTASK + 3) / 4), blk, 0, stream>>>(qkvb, rel, wout);
    // 3. fold + /counts + pack for proj
    fold_pack_kernel<<<dim3(1728), blk, 0, stream>>>(wout, Dr, Di);
    // 4. proj gemm -> bf16 planar pm
    cgemm_mfma_kernel<96, 3, 3><<<dim3(3 * 144), blk, 0, stream>>>(
        wp, wp + 9216, wp + 18432, Dr, Di, pm_r, pm_i, PIX);
    // 5. s1 = x + proj -> packed bf16 + BN1 stats
    combine_pack_kernel<<<dim3(432), blk, 0, stream>>>(x_r, x_i, pm_r, pm_i, Dr, Di, ssum1);
    // 6. build BN1-folded mlp1 weights + bias
    scale_w_kernel<<<dim3(579), blk, 0, stream>>>(
        mlp1_wr, mlp1_wi, n1_gr, n1_br, n1_gi, n1_bi, ssum1,
        W1s, W1s + 36864, W1s + 73728, W1s + 110592, biasR, biasI);
    // 7. mlp1 (BN folded) + bias + cgelu -> packed hidden
    mlp1bn_kernel<<<dim3(12 * 144), blk, 0, stream>>>(
        W1s, W1s + 36864, W1s + 73728, W1s + 110592, biasR, biasI,
        Dr, Di, hid_r, hid_i, PIX);
    // 8. mlp2 gemm -> m (bf16 planar pm)
    cgemm_mfma_kernel<384, 3, 3><<<dim3(3 * 144), blk, 0, stream>>>(
        w2, w2 + 36864, w2 + 73728, hid_r, hid_i, pm_r, pm_i, PIX);
    // 9. s2 = m + bn1(s1) -> bf16 planar + BN2 stats
    addbn_kernel<<<dim3(432), blk, 0, stream>>>(Dr, Di, ssum1,
        n1_gr, n1_br, n1_gi, n1_bi, pm_r, pm_i, s2r, s2i, ssum2);
    // 10. BN2 apply -> out
    bn_apply_kernel<<<dim3(13824), blk, 0, stream>>>(s2r, s2i,
        n2_gr, n2_br, n2_gi, n2_bi, ssum2, out_r, out_i);
}